// Round 6
// baseline (1640.988 us; speedup 1.0000x reference)
//
#include <hip/hip_runtime.h>
#include <cstdint>

typedef unsigned short u16;
typedef __attribute__((ext_vector_type(8))) __bf16 bf16x8;
typedef __attribute__((ext_vector_type(4))) float f32x4;

#define TOK 4096
#define DM  1024
#define EXP 8
#define FF  4096
#define SEQ 512
#define NH  8
#define HD  128
#define JOBCAP 9216

__device__ __forceinline__ u16 f2bf(float f) {
  union { float f; unsigned int u; } v; v.f = f;
  unsigned int u = v.u;
  u += 0x7FFFu + ((u >> 16) & 1u);   // round-to-nearest-even
  return (u16)(u >> 16);
}

// async global->LDS, 16B per lane; dest = wave-uniform base + lane*16
__device__ __forceinline__ void gl_lds16(const u16* g, u16* l) {
  __builtin_amdgcn_global_load_lds(
      (const __attribute__((address_space(1))) unsigned int*)g,
      (__attribute__((address_space(3))) unsigned int*)l, 16, 0, 0);
}

// ---------------- embed gather ----------------
__global__ void k_embed(const int* __restrict__ ids, const float* __restrict__ emb,
                        float* __restrict__ x) {
  int t = blockIdx.x;
  int id = ids[t];
  const float4* src = (const float4*)(emb + (size_t)id * DM);
  float4* dst = (float4*)(x + (size_t)t * DM);
  dst[threadIdx.x] = src[threadIdx.x];
}

// ---------------- layernorm -> f32 and/or bf16 ----------------
__global__ void k_ln(const float* __restrict__ in, const float* __restrict__ g,
                     const float* __restrict__ be, float* __restrict__ of32,
                     u16* __restrict__ obf) {
  int t = blockIdx.x, tid = threadIdx.x;
  float4 v = ((const float4*)(in + (size_t)t * DM))[tid];
  float s = v.x + v.y + v.z + v.w;
  float sq = v.x*v.x + v.y*v.y + v.z*v.z + v.w*v.w;
  for (int o = 32; o; o >>= 1) { s += __shfl_down(s, o); sq += __shfl_down(sq, o); }
  __shared__ float ss[4], sqs[4];
  if ((tid & 63) == 0) { ss[tid >> 6] = s; sqs[tid >> 6] = sq; }
  __syncthreads();
  s  = ss[0] + ss[1] + ss[2] + ss[3];
  sq = sqs[0] + sqs[1] + sqs[2] + sqs[3];
  float mean = s * (1.f / DM);
  float var  = sq * (1.f / DM) - mean * mean;
  float rstd = rsqrtf(var + 1e-5f);
  float4 gg = ((const float4*)g)[tid];
  float4 bb = ((const float4*)be)[tid];
  float4 o4;
  o4.x = (v.x - mean) * rstd * gg.x + bb.x;
  o4.y = (v.y - mean) * rstd * gg.y + bb.y;
  o4.z = (v.z - mean) * rstd * gg.z + bb.z;
  o4.w = (v.w - mean) * rstd * gg.w + bb.w;
  if (of32) ((float4*)(of32 + (size_t)t * DM))[tid] = o4;
  if (obf) {
    ushort4 u; u.x = f2bf(o4.x); u.y = f2bf(o4.y); u.z = f2bf(o4.z); u.w = f2bf(o4.w);
    ((ushort4*)(obf + (size_t)t * DM))[tid] = u;
  }
}

// ---------------- transpose f32->f32 and f32->bf16 ----------------
__global__ void k_tcvtf(const float* __restrict__ src, float* __restrict__ dst, int K, int N) {
  __shared__ float t[32][33];
  int k0 = blockIdx.x * 32, n0 = blockIdx.y * 32;
  int tx = threadIdx.x, ty = threadIdx.y;
  #pragma unroll
  for (int i = 0; i < 4; i++) t[ty + 8*i][tx] = src[(size_t)(k0 + ty + 8*i) * N + n0 + tx];
  __syncthreads();
  #pragma unroll
  for (int i = 0; i < 4; i++) dst[(size_t)(n0 + ty + 8*i) * K + k0 + tx] = t[tx][ty + 8*i];
}

__global__ void k_tcvt(const float* __restrict__ src, u16* __restrict__ dst, int K, int N) {
  __shared__ float t[32][33];
  size_t zoff = (size_t)blockIdx.z * K * N;
  src += zoff;
  u16* d = dst + zoff;
  int k0 = blockIdx.x * 32, n0 = blockIdx.y * 32;
  int tx = threadIdx.x, ty = threadIdx.y;
  #pragma unroll
  for (int i = 0; i < 4; i++) t[ty + 8*i][tx] = src[(size_t)(k0 + ty + 8*i) * N + n0 + tx];
  __syncthreads();
  int u = ty * 32 + tx;
  int r = u >> 3;            // output row (n offset)
  int kq = u & 7;            // k quad
  ushort4 o;
  o.x = f2bf(t[kq*4+0][r]); o.y = f2bf(t[kq*4+1][r]);
  o.z = f2bf(t[kq*4+2][r]); o.w = f2bf(t[kq*4+3][r]);
  *(ushort4*)&d[(size_t)(n0 + r) * K + k0 + kq*4] = o;
}

// ---------------- fp32 vector 64x64 TN GEMM (attention path: router exactness) ----------------
constexpr int FOP_PLAIN  = 0;
constexpr int FOP_VT     = 1;
constexpr int FOP_SCORES = 2;
constexpr int FOP_ATTO   = 3;
constexpr int FOP_PROJ   = 4;

struct GemmFArgs {
  const float* A; const float* B; float* C;
  const float* bias; const float* resid; const float* pos;
  int lda, ldb, ldc, K;
};

template<int OP>
__launch_bounds__(256)
__global__ void gemm_f(GemmFArgs p) {
  int bx = blockIdx.x, by = blockIdx.y, z = blockIdx.z;
  if constexpr (OP == FOP_SCORES) { if (by > bx) return; }
  const float *Abase, *Bbase;
  if constexpr (OP == FOP_SCORES) {
    Abase = p.A + (size_t)(z >> 3) * 524288 + (z & 7) * 128;
    Bbase = p.B + (size_t)(z >> 3) * 524288 + (z & 7) * 128;
  } else if constexpr (OP == FOP_ATTO) {
    Abase = p.A + (size_t)z * 262144;
    Bbase = p.B + (size_t)z * 65536;
  } else { Abase = p.A; Bbase = p.B; }

  __shared__ float As[16][68], Bs[16][68];
  int tid = threadIdx.x;
  int sr = tid >> 2, sc = (tid & 3) * 4;
  int tx = tid & 15, ty = tid >> 4;

  float acc[4][4] = {};
  int kmax = p.K;
  if constexpr (OP == FOP_ATTO) { int lim = bx * 64 + 64; kmax = lim < p.K ? lim : p.K; }

  for (int k0 = 0; k0 < kmax; k0 += 16) {
    float4 av = *(const float4*)(Abase + (size_t)(bx * 64 + sr) * p.lda + k0 + sc);
    float4 bv = *(const float4*)(Bbase + (size_t)(by * 64 + sr) * p.ldb + k0 + sc);
    As[sc + 0][sr] = av.x; As[sc + 1][sr] = av.y; As[sc + 2][sr] = av.z; As[sc + 3][sr] = av.w;
    Bs[sc + 0][sr] = bv.x; Bs[sc + 1][sr] = bv.y; Bs[sc + 2][sr] = bv.z; Bs[sc + 3][sr] = bv.w;
    __syncthreads();
    #pragma unroll
    for (int k = 0; k < 16; ++k) {
      float4 a = *(const float4*)&As[k][ty * 4];
      float4 b = *(const float4*)&Bs[k][tx * 4];
      acc[0][0] += a.x * b.x; acc[0][1] += a.x * b.y; acc[0][2] += a.x * b.z; acc[0][3] += a.x * b.w;
      acc[1][0] += a.y * b.x; acc[1][1] += a.y * b.y; acc[1][2] += a.y * b.z; acc[1][3] += a.y * b.w;
      acc[2][0] += a.z * b.x; acc[2][1] += a.z * b.y; acc[2][2] += a.z * b.z; acc[2][3] += a.z * b.w;
      acc[3][0] += a.w * b.x; acc[3][1] += a.w * b.y; acc[3][2] += a.w * b.z; acc[3][3] += a.w * b.w;
    }
    __syncthreads();
  }

  #pragma unroll
  for (int i = 0; i < 4; ++i) {
    int m = bx * 64 + ty * 4 + i;
    #pragma unroll
    for (int j = 0; j < 4; ++j) {
      int n = by * 64 + tx * 4 + j;
      float v = acc[i][j];
      if constexpr (OP == FOP_PLAIN) {
        p.C[(size_t)m * p.ldc + n] = v;
      } else if constexpr (OP == FOP_VT) {
        p.C[(size_t)((m >> 9) * 8 + (n >> 7)) * 65536 + (size_t)(n & 127) * 512 + (m & 511)] = v;
      } else if constexpr (OP == FOP_SCORES) {
        p.C[(size_t)z * 262144 + (size_t)m * 512 + n] = v;
      } else if constexpr (OP == FOP_ATTO) {
        p.C[(size_t)(z >> 3) * 524288 + (size_t)m * 1024 + (z & 7) * 128 + n] = v;
      } else if constexpr (OP == FOP_PROJ) {
        size_t idx = (size_t)m * 1024 + n;
        p.C[idx] = v + p.bias[n] + p.resid[idx] + p.pos[(size_t)(m & 511) * 1024 + n];
      }
    }
  }
}

// ---------------- causal softmax, f32 in place ----------------
__global__ void k_softmax_f(float* __restrict__ scores) {
  int q = blockIdx.x, bh = blockIdx.y, tid = threadIdx.x;
  float* row = scores + ((size_t)bh * 512 + q) * 512;
  const float scale = 0.088388347648318447f; // 128^-0.5
  int j0 = tid * 2;
  float v0 = -1e30f, v1 = -1e30f;
  if (j0 <= q)     v0 = row[j0] * scale;
  if (j0 + 1 <= q) v1 = row[j0 + 1] * scale;
  float m = fmaxf(v0, v1);
  for (int o = 32; o; o >>= 1) m = fmaxf(m, __shfl_down(m, o));
  __shared__ float sm[4], ssum[4];
  if ((tid & 63) == 0) sm[tid >> 6] = m;
  __syncthreads();
  m = fmaxf(fmaxf(sm[0], sm[1]), fmaxf(sm[2], sm[3]));
  float p0 = (j0 <= q)     ? expf(v0 - m) : 0.f;
  float p1 = (j0 + 1 <= q) ? expf(v1 - m) : 0.f;
  float s = p0 + p1;
  for (int o = 32; o; o >>= 1) s += __shfl_down(s, o);
  if ((tid & 63) == 0) ssum[tid >> 6] = s;
  __syncthreads();
  s = ssum[0] + ssum[1] + ssum[2] + ssum[3];
  float inv = 1.f / s;
  row[j0]     = p0 * inv;
  row[j0 + 1] = p1 * inv;
}

// ---------------- bf16 MFMA 128x128 TN GEMM, 3-buffer counted-vmcnt pipeline ----------------
// BM=BN=128, BK=32; 4 waves x (4x4 frags of 16x16x32). T2 both-sides swizzle:
// source col pre-swizzled (((l&3)^((l>>2)&3))*8), read at fk^((fm&3)*8).
constexpr int OP_MOE1 = 0; // gathered A rows, bf16 C=relu(acc+b1[e])
constexpr int OP_MOE2 = 1; // contiguous padded A rows, f32 C=acc+b2[e]

struct GemmArgs {
  const u16* A; const u16* B; void* C;
  const float* bias;
  const int* joblist; const int* seg;
  int lda, ldb, K;
};

template<int OP>
__launch_bounds__(256)
__global__ void gemm_k(GemmArgs p) {
  int r0g = blockIdx.x * 128;              // global padded row of this tile
  if (r0g >= p.seg[8]) return;
  int z = 0;
  #pragma unroll
  for (int e = 1; e < 8; ++e) z += (r0g >= p.seg[e]) ? 1 : 0;
  int by = blockIdx.y;
  const u16* Bbase = p.B + (size_t)z * 4194304;

  __shared__ __align__(16) u16 As[3 * 4096];
  __shared__ __align__(16) u16 Bs[3 * 4096];

  int tid = threadIdx.x;
  int lane = tid & 63, wid = tid >> 6;

  int srow = wid * 16 + (lane >> 2);
  int skoff = ((lane & 3) ^ ((lane >> 2) & 3)) * 8;   // pre-swizzled source col (u16 units)

  const u16 *aptr0, *aptr1;
  if constexpr (OP == OP_MOE1) {
    int j0 = p.joblist[r0g + srow];
    int j1 = p.joblist[r0g + 64 + srow];
    aptr0 = p.A + (size_t)(j0 < 0 ? 0 : j0) * p.lda + skoff;
    aptr1 = p.A + (size_t)(j1 < 0 ? 0 : j1) * p.lda + skoff;
  } else {
    aptr0 = p.A + (size_t)(r0g + srow) * p.lda + skoff;
    aptr1 = p.A + (size_t)(r0g + 64 + srow) * p.lda + skoff;
  }
  const u16* bptr0 = Bbase + (size_t)(by * 128 + srow) * p.ldb + skoff;
  const u16* bptr1 = Bbase + (size_t)(by * 128 + 64 + srow) * p.ldb + skoff;

  int lo0 = (wid * 16) * 32;        // LDS chunk offsets (u16 units)
  int lo1 = ((wid + 4) * 16) * 32;

  int wr = wid >> 1, wc = wid & 1;
  int fm = lane & 15;
  int fk = (lane >> 4) * 8;
  int sfk = fk ^ ((fm & 3) * 8);    // swizzled read col (u16 units)

  f32x4 acc[4][4] = {};
  int nt = p.K >> 5;

#define STAGE_T(T, BUF) { int _k0 = (T) * 32; int _b = (BUF) * 4096;       \
    gl_lds16(aptr0 + _k0, &As[_b + lo0]); gl_lds16(aptr1 + _k0, &As[_b + lo1]); \
    gl_lds16(bptr0 + _k0, &Bs[_b + lo0]); gl_lds16(bptr1 + _k0, &Bs[_b + lo1]); }

  // prologue: 2 tiles in flight
  STAGE_T(0, 0);
  STAGE_T(1, 1);

  for (int t = 0; t < nt; ++t) {
    if (t + 2 < nt) STAGE_T(t + 2, (t + 2) % 3);
    // wait until MY tile-t loads (oldest 4) are done; keep rest in flight
    if (t + 2 < nt)      asm volatile("s_waitcnt vmcnt(8)" ::: "memory");
    else if (t + 1 < nt) asm volatile("s_waitcnt vmcnt(4)" ::: "memory");
    else                 asm volatile("s_waitcnt vmcnt(0)" ::: "memory");
    __builtin_amdgcn_sched_barrier(0);
    __builtin_amdgcn_s_barrier();          // tile t valid in LDS for all waves
    __builtin_amdgcn_sched_barrier(0);

    int cb = (t % 3) * 4096;
    bf16x8 af[4], bfr[4];
    #pragma unroll
    for (int i = 0; i < 4; ++i) {
      af[i]  = *(const bf16x8*)&As[cb + (wr * 64 + i * 16 + fm) * 32 + sfk];
      bfr[i] = *(const bf16x8*)&Bs[cb + (wc * 64 + i * 16 + fm) * 32 + sfk];
    }
    #pragma unroll
    for (int mi = 0; mi < 4; ++mi)
      #pragma unroll
      for (int ni = 0; ni < 4; ++ni)
        acc[mi][ni] = __builtin_amdgcn_mfma_f32_16x16x32_bf16(af[mi], bfr[ni], acc[mi][ni], 0, 0, 0);

    asm volatile("s_waitcnt lgkmcnt(0)" ::: "memory");
    __builtin_amdgcn_sched_barrier(0);
    __builtin_amdgcn_s_barrier();          // all waves done reading buf t -> may be overwritten
    __builtin_amdgcn_sched_barrier(0);
  }
#undef STAGE_T

  int rb = (lane >> 4) * 4;
  int cl = lane & 15;
  #pragma unroll
  for (int mi = 0; mi < 4; ++mi)
    #pragma unroll
    for (int ni = 0; ni < 4; ++ni)
      #pragma unroll
      for (int j = 0; j < 4; ++j) {
        int m = r0g + wr * 64 + mi * 16 + rb + j;       // global padded row
        int n = by * 128 + wc * 64 + ni * 16 + cl;
        float v = acc[mi][ni][j];
        if constexpr (OP == OP_MOE1) {
          float t2 = v + p.bias[(size_t)z * FF + n];
          t2 = t2 > 0.f ? t2 : 0.f;
          ((u16*)p.C)[(size_t)m * FF + n] = f2bf(t2);
        } else {
          ((float*)p.C)[(size_t)m * DM + n] = v + p.bias[(size_t)z * DM + n];
        }
      }
}

// ---------------- router: inline fp32 LN + logits + noisy top-2 + gates ----------------
__global__ void k_router(const float* __restrict__ xin, const float* __restrict__ g,
                         const float* __restrict__ be,
                         const float* __restrict__ Wr, const float* __restrict__ br,
                         const float* __restrict__ Wn, const float* __restrict__ bn,
                         const float* __restrict__ noise,
                         float* __restrict__ gates, int* __restrict__ topidx) {
  int t = blockIdx.x, tid = threadIdx.x;
  float4 v = ((const float4*)(xin + (size_t)t * DM))[tid];
  float s = v.x + v.y + v.z + v.w;
  float sq = v.x*v.x + v.y*v.y + v.z*v.z + v.w*v.w;
  for (int o = 32; o; o >>= 1) { s += __shfl_down(s, o); sq += __shfl_down(sq, o); }
  __shared__ float ss[4], sqs[4];
  if ((tid & 63) == 0) { ss[tid >> 6] = s; sqs[tid >> 6] = sq; }
  __syncthreads();
  s  = ss[0] + ss[1] + ss[2] + ss[3];
  sq = sqs[0] + sqs[1] + sqs[2] + sqs[3];
  float mean = s * (1.f / DM);
  float var  = sq * (1.f / DM) - mean * mean;
  float rstd = rsqrtf(var + 1e-5f);
  float4 gg = ((const float4*)g)[tid];
  float4 bb = ((const float4*)be)[tid];
  float xl[4];
  xl[0] = (v.x - mean) * rstd * gg.x + bb.x;
  xl[1] = (v.y - mean) * rstd * gg.y + bb.y;
  xl[2] = (v.z - mean) * rstd * gg.z + bb.z;
  xl[3] = (v.w - mean) * rstd * gg.w + bb.w;
  float pl[8], pn[8];
  #pragma unroll
  for (int e = 0; e < 8; e++) { pl[e] = 0.f; pn[e] = 0.f; }
  #pragma unroll
  for (int j = 0; j < 4; j++) {
    int d = tid * 4 + j;
    float xv = xl[j];
    const float4* wr = (const float4*)(Wr + (size_t)d * 8);
    const float4* wn = (const float4*)(Wn + (size_t)d * 8);
    float4 a0 = wr[0], a1 = wr[1], c0 = wn[0], c1 = wn[1];
    pl[0] += xv * a0.x; pl[1] += xv * a0.y; pl[2] += xv * a0.z; pl[3] += xv * a0.w;
    pl[4] += xv * a1.x; pl[5] += xv * a1.y; pl[6] += xv * a1.z; pl[7] += xv * a1.w;
    pn[0] += xv * c0.x; pn[1] += xv * c0.y; pn[2] += xv * c0.z; pn[3] += xv * c0.w;
    pn[4] += xv * c1.x; pn[5] += xv * c1.y; pn[6] += xv * c1.z; pn[7] += xv * c1.w;
  }
  for (int o = 32; o; o >>= 1) {
    #pragma unroll
    for (int e = 0; e < 8; e++) { pl[e] += __shfl_down(pl[e], o); pn[e] += __shfl_down(pn[e], o); }
  }
  __shared__ float sl[4][8], sn[4][8];
  if ((tid & 63) == 0) {
    int w = tid >> 6;
    #pragma unroll
    for (int e = 0; e < 8; e++) { sl[w][e] = pl[e]; sn[w][e] = pn[e]; }
  }
  __syncthreads();
  if (tid == 0) {
    float noisy[8];
    #pragma unroll
    for (int e = 0; e < 8; e++) {
      float l  = sl[0][e] + sl[1][e] + sl[2][e] + sl[3][e] + br[e];
      float nn = sn[0][e] + sn[1][e] + sn[2][e] + sn[3][e] + bn[e];
      float sp = (nn > 20.f) ? nn : log1pf(expf(nn));
      noisy[e] = l + noise[(size_t)t * 8 + e] * sp;
    }
    int i0 = 0;
    for (int e = 1; e < 8; e++) if (noisy[e] > noisy[i0]) i0 = e;
    int i1 = (i0 == 0) ? 1 : 0;
    for (int e = 0; e < 8; e++) if (e != i0 && noisy[e] > noisy[i1]) i1 = e;
    float e1 = expf(noisy[i1] - noisy[i0]);
    float zz = 1.f + e1;
    gates[t * 2] = 1.f / zz; gates[t * 2 + 1] = e1 / zz;
    topidx[t * 2] = i0; topidx[t * 2 + 1] = i1;
  }
}

// ---------------- MoE bookkeeping ----------------
__global__ void k_moe_init(int* cnt, int* cnt2, int* joblist) {
  int i = blockIdx.x * 256 + threadIdx.x;
  if (i < JOBCAP) joblist[i] = -1;
  if (i < 8) { cnt[i] = 0; cnt2[i] = 0; }
}
__global__ void k_moe_count(const int* __restrict__ topidx, int* __restrict__ cnt) {
  int t = blockIdx.x * 256 + threadIdx.x;
  if (t >= TOK) return;
  atomicAdd(&cnt[topidx[t * 2]], 1);
  atomicAdd(&cnt[topidx[t * 2 + 1]], 1);
}
__global__ void k_moe_offsets(const int* __restrict__ cnt, int* __restrict__ seg) {
  if (threadIdx.x == 0) {
    int o = 0;
    for (int e = 0; e < 8; e++) { seg[e] = o; o += (cnt[e] + 127) & ~127; }  // pad to BM=128
    seg[8] = o;
  }
}
__global__ void k_moe_scatter(const int* __restrict__ topidx, int* __restrict__ cnt2,
                              const int* __restrict__ seg, int* __restrict__ joblist,
                              int* __restrict__ tokpos) {
  int t = blockIdx.x * 256 + threadIdx.x;
  if (t >= TOK) return;
  #pragma unroll
  for (int s = 0; s < 2; s++) {
    int e = topidx[t * 2 + s];
    int p = atomicAdd(&cnt2[e], 1);
    int pos = seg[e] + p;
    joblist[pos] = t;
    tokpos[t * 2 + s] = pos;
  }
}
__global__ void k_combine(const float* __restrict__ y, const float* __restrict__ gates,
                          const int* __restrict__ tokpos, float* __restrict__ out) {
  int t = blockIdx.x, tid = threadIdx.x;
  int p0 = tokpos[t * 2], p1 = tokpos[t * 2 + 1];
  float g0 = gates[t * 2], g1 = gates[t * 2 + 1];
  float4 a = ((const float4*)(y + (size_t)p0 * DM))[tid];
  float4 b = ((const float4*)(y + (size_t)p1 * DM))[tid];
  float4 o;
  o.x = g0 * a.x + g1 * b.x; o.y = g0 * a.y + g1 * b.y;
  o.z = g0 * a.z + g1 * b.z; o.w = g0 * a.w + g1 * b.w;
  ((float4*)(out + (size_t)t * DM))[tid] = o;
}

// ---------------- feature mean + classifier ----------------
__global__ void k_feature(const float* __restrict__ second, float* __restrict__ feat) {
  int i = blockIdx.x * 256 + threadIdx.x;
  if (i >= 8 * DM) return;
  int b = i >> 10, d = i & 1023;
  const float* p = second + (size_t)b * SEQ * DM + d;
  float s = 0.f;
  for (int j = 0; j < SEQ; j++) s += p[(size_t)j * DM];
  feat[i] = s * (1.f / SEQ);
}
__global__ void k_cls(const float* __restrict__ feat, const float* __restrict__ Wc,
                      const float* __restrict__ bc, float* __restrict__ cls) {
  int o = blockIdx.x; int b = o / 10, n = o % 10; int l = threadIdx.x;
  float s = 0.f;
  for (int d = l; d < DM; d += 64) s += feat[b * DM + d] * Wc[(size_t)d * 10 + n];
  for (int off = 32; off; off >>= 1) s += __shfl_down(s, off);
  if (l == 0) cls[o] = s + bc[n];
}

// ---------------- launch ----------------
extern "C" void kernel_launch(void* const* d_in, const int* in_sizes, int n_in,
                              void* d_out, int out_size, void* d_ws, size_t ws_size,
                              hipStream_t stream) {
  const int*   ids    = (const int*)d_in[0];
  const float* emb    = (const float*)d_in[2];
  const float* pos    = (const float*)d_in[3];
  const float* Wq     = (const float*)d_in[4];
  const float* Wk     = (const float*)d_in[5];
  const float* Wv     = (const float*)d_in[6];
  const float* Wo     = (const float*)d_in[7];
  const float* bo     = (const float*)d_in[8];
  const float* g1     = (const float*)d_in[9];
  const float* be1    = (const float*)d_in[10];
  const float* g2     = (const float*)d_in[11];
  const float* be2    = (const float*)d_in[12];
  const float* g3     = (const float*)d_in[13];
  const float* be3    = (const float*)d_in[14];
  const float* Wr1    = (const float*)d_in[15];
  const float* br1    = (const float*)d_in[16];
  const float* Wn1    = (const float*)d_in[17];
  const float* bn1    = (const float*)d_in[18];
  const float* W1a    = (const float*)d_in[19];
  const float* b1a    = (const float*)d_in[20];
  const float* W2a    = (const float*)d_in[21];
  const float* b2a    = (const float*)d_in[22];
  const float* Wr2    = (const float*)d_in[23];
  const float* br2    = (const float*)d_in[24];
  const float* Wn2    = (const float*)d_in[25];
  const float* bn2    = (const float*)d_in[26];
  const float* W1b    = (const float*)d_in[27];
  const float* b1b    = (const float*)d_in[28];
  const float* W2b    = (const float*)d_in[29];
  const float* b2b    = (const float*)d_in[30];
  const float* noise1 = (const float*)d_in[31];
  const float* noise2 = (const float*)d_in[32];
  const float* Wc     = (const float*)d_in[33];
  const float* bc     = (const float*)d_in[34];

  char* wsp = (char*)d_ws; size_t off = 0;
  auto alloc = [&](size_t bytes) -> void* {
    void* p = wsp + off; off += (bytes + 255) & ~(size_t)255; return p;
  };
  // ---- workspace (~223 MB; ws_size >= 448MB per round-1 evidence) ----
  char*  G     = (char*)alloc(180355072);              // phase-overlaid big region
  float* x     = (float*)alloc((size_t)TOK * DM * 4);
  float* x2    = (float*)alloc((size_t)TOK * DM * 4);
  u16*   xlnb  = (u16*)alloc((size_t)TOK * DM * 2);
  float* gates  = (float*)alloc(TOK * 2 * 4);
  int*   topidx = (int*)alloc(TOK * 2 * 4);
  int*   cnt    = (int*)alloc(8 * 4);
  int*   cnt2   = (int*)alloc(8 * 4);
  int*   seg    = (int*)alloc(16 * 4);
  int*   joblist= (int*)alloc(JOBCAP * 4);
  int*   tokpos = (int*)alloc(TOK * 2 * 4);
  (void)ws_size; (void)in_sizes; (void)n_in; (void)out_size;

  // attention-phase views (151MB)
  float* WQT  = (float*)(G + 0);
  float* WKT  = (float*)(G + 4194304);
  float* WVT  = (float*)(G + 8388608);
  float* WOT  = (float*)(G + 12582912);
  float* QB   = (float*)(G + 16777216);   // q; reused as o
  float* KB   = (float*)(G + 33554432);
  float* VT   = (float*)(G + 50331648);   // [b][h][d][s]
  float* SC   = (float*)(G + 67108864);   // scores/att f32 [64][512][512]
  float* XLNF = (float*)(G + 134217728);
  // moe-phase views (180MB)
  u16*   H    = (u16*)(G + 0);            // [9216][4096] bf16
  float* Y    = (float*)(G + 75497472);   // [9216][1024] f32
  u16*   WBUF = (u16*)(G + 113246208);    // expert weights bf16, reused W1->W2

  float* out_first  = (float*)d_out;
  float* out_second = out_first + (size_t)TOK * DM;
  float* feat       = out_first + (size_t)2 * TOK * DM;
  float* cls        = feat + 8 * DM;

  dim3 tb(32, 8);
  // ---- attention phase (pure fp32: router input must match numpy to ~1e-6) ----
  hipLaunchKernelGGL(k_tcvtf, dim3(32, 32, 1), tb, 0, stream, Wq, WQT, DM, DM);
  hipLaunchKernelGGL(k_tcvtf, dim3(32, 32, 1), tb, 0, stream, Wk, WKT, DM, DM);
  hipLaunchKernelGGL(k_tcvtf, dim3(32, 32, 1), tb, 0, stream, Wv, WVT, DM, DM);
  hipLaunchKernelGGL(k_tcvtf, dim3(32, 32, 1), tb, 0, stream, Wo, WOT, DM, DM);
  hipLaunchKernelGGL(k_embed, dim3(TOK), dim3(256), 0, stream, ids, emb, x);
  hipLaunchKernelGGL(k_ln, dim3(TOK), dim3(256), 0, stream, x, g1, be1, XLNF, (u16*)nullptr);

  GemmFArgs a{};
  a.A = XLNF; a.B = WQT; a.C = QB; a.lda = DM; a.ldb = DM; a.ldc = DM; a.K = DM;
  hipLaunchKernelGGL(gemm_f<FOP_PLAIN>, dim3(64, 16, 1), dim3(256), 0, stream, a);
  a.B = WKT; a.C = KB;
  hipLaunchKernelGGL(gemm_f<FOP_PLAIN>, dim3(64, 16, 1), dim3(256), 0, stream, a);
  a.B = WVT; a.C = VT;
  hipLaunchKernelGGL(gemm_f<FOP_VT>, dim3(64, 16, 1), dim3(256), 0, stream, a);

  GemmFArgs sg{};
  sg.A = QB; sg.B = KB; sg.C = SC; sg.lda = DM; sg.ldb = DM; sg.ldc = SEQ; sg.K = HD;
  hipLaunchKernelGGL(gemm_f<FOP_SCORES>, dim3(8, 8, 64), dim3(256), 0, stream, sg);
  hipLaunchKernelGGL(k_softmax_f, dim3(SEQ, 64), dim3(256), 0, stream, SC);

  GemmFArgs og{};
  og.A = SC; og.B = VT; og.C = QB;
  og.lda = SEQ; og.ldb = SEQ; og.ldc = DM; og.K = SEQ;
  hipLaunchKernelGGL(gemm_f<FOP_ATTO>, dim3(8, 2, 64), dim3(256), 0, stream, og);

  GemmFArgs pg{};
  pg.A = QB; pg.B = WOT; pg.C = x2; pg.bias = bo; pg.resid = x; pg.pos = pos;
  pg.lda = DM; pg.ldb = DM; pg.ldc = DM; pg.K = DM;
  hipLaunchKernelGGL(gemm_f<FOP_PROJ>, dim3(64, 16, 1), dim3(256), 0, stream, pg);

  // ---- MoE phase (bf16 MFMA experts; router fp32) ----
  auto run_moe = [&](const float* g, const float* be, const float* Wr, const float* br,
                     const float* Wn, const float* bn, const float* noise,
                     const float* W1, const float* b1, const float* W2, const float* b2,
                     float* outp) {
    hipLaunchKernelGGL(k_ln, dim3(TOK), dim3(256), 0, stream, x2, g, be, (float*)nullptr, xlnb);
    hipLaunchKernelGGL(k_router, dim3(TOK), dim3(256), 0, stream, x2, g, be, Wr, br, Wn, bn, noise, gates, topidx);
    hipLaunchKernelGGL(k_moe_init, dim3(36), dim3(256), 0, stream, cnt, cnt2, joblist);
    hipLaunchKernelGGL(k_moe_count, dim3(16), dim3(256), 0, stream, topidx, cnt);
    hipLaunchKernelGGL(k_moe_offsets, dim3(1), dim3(64), 0, stream, cnt, seg);
    hipLaunchKernelGGL(k_moe_scatter, dim3(16), dim3(256), 0, stream, topidx, cnt2, seg, joblist, tokpos);
    hipLaunchKernelGGL(k_tcvt, dim3(32, 128, 8), tb, 0, stream, W1, WBUF, DM, FF);
    GemmArgs m1{};
    m1.A = xlnb; m1.B = WBUF; m1.C = H; m1.bias = b1; m1.joblist = joblist; m1.seg = seg;
    m1.lda = DM; m1.ldb = DM; m1.K = DM;
    hipLaunchKernelGGL(gemm_k<OP_MOE1>, dim3(72, 32), dim3(256), 0, stream, m1);
    hipLaunchKernelGGL(k_tcvt, dim3(128, 32, 8), tb, 0, stream, W2, WBUF, FF, DM);
    GemmArgs m2{};
    m2.A = H; m2.B = WBUF; m2.C = Y; m2.bias = b2; m2.seg = seg;
    m2.lda = FF; m2.ldb = FF; m2.K = FF;
    hipLaunchKernelGGL(gemm_k<OP_MOE2>, dim3(72, 8), dim3(256), 0, stream, m2);
    hipLaunchKernelGGL(k_combine, dim3(TOK), dim3(256), 0, stream, Y, gates, tokpos, outp);
  };
  run_moe(g2, be2, Wr1, br1, Wn1, bn1, noise1, W1a, b1a, W2a, b2a, out_first);
  run_moe(g3, be3, Wr2, br2, Wn2, bn2, noise2, W1b, b1b, W2b, b2b, out_second);

  hipLaunchKernelGGL(k_feature, dim3(32), dim3(256), 0, stream, out_second, feat);
  hipLaunchKernelGGL(k_cls, dim3(80), dim3(64), 0, stream, feat, Wc, bc, cls);
}

// Round 7
// 1580.504 us; speedup vs baseline: 1.0383x; 1.0383x over previous
//
#include <hip/hip_runtime.h>
#include <cstdint>

typedef unsigned short u16;
typedef __attribute__((ext_vector_type(8))) __bf16 bf16x8;
typedef __attribute__((ext_vector_type(4))) float f32x4;

#define TOK 4096
#define DM  1024
#define EXP 8
#define FF  4096
#define SEQ 512
#define NH  8
#define HD  128
#define JOBCAP 9216

__device__ __forceinline__ u16 f2bf(float f) {
  union { float f; unsigned int u; } v; v.f = f;
  unsigned int u = v.u;
  u += 0x7FFFu + ((u >> 16) & 1u);   // round-to-nearest-even
  return (u16)(u >> 16);
}

// async global->LDS, 16B per lane; dest = wave-uniform base + lane*16
__device__ __forceinline__ void gl_lds16(const u16* g, u16* l) {
  __builtin_amdgcn_global_load_lds(
      (const __attribute__((address_space(1))) unsigned int*)g,
      (__attribute__((address_space(3))) unsigned int*)l, 16, 0, 0);
}

// ---------------- embed gather ----------------
__global__ void k_embed(const int* __restrict__ ids, const float* __restrict__ emb,
                        float* __restrict__ x) {
  int t = blockIdx.x;
  int id = ids[t];
  const float4* src = (const float4*)(emb + (size_t)id * DM);
  float4* dst = (float4*)(x + (size_t)t * DM);
  dst[threadIdx.x] = src[threadIdx.x];
}

// ---------------- layernorm -> f32 and/or bf16 ----------------
__global__ void k_ln(const float* __restrict__ in, const float* __restrict__ g,
                     const float* __restrict__ be, float* __restrict__ of32,
                     u16* __restrict__ obf) {
  int t = blockIdx.x, tid = threadIdx.x;
  float4 v = ((const float4*)(in + (size_t)t * DM))[tid];
  float s = v.x + v.y + v.z + v.w;
  float sq = v.x*v.x + v.y*v.y + v.z*v.z + v.w*v.w;
  for (int o = 32; o; o >>= 1) { s += __shfl_down(s, o); sq += __shfl_down(sq, o); }
  __shared__ float ss[4], sqs[4];
  if ((tid & 63) == 0) { ss[tid >> 6] = s; sqs[tid >> 6] = sq; }
  __syncthreads();
  s  = ss[0] + ss[1] + ss[2] + ss[3];
  sq = sqs[0] + sqs[1] + sqs[2] + sqs[3];
  float mean = s * (1.f / DM);
  float var  = sq * (1.f / DM) - mean * mean;
  float rstd = rsqrtf(var + 1e-5f);
  float4 gg = ((const float4*)g)[tid];
  float4 bb = ((const float4*)be)[tid];
  float4 o4;
  o4.x = (v.x - mean) * rstd * gg.x + bb.x;
  o4.y = (v.y - mean) * rstd * gg.y + bb.y;
  o4.z = (v.z - mean) * rstd * gg.z + bb.z;
  o4.w = (v.w - mean) * rstd * gg.w + bb.w;
  if (of32) ((float4*)(of32 + (size_t)t * DM))[tid] = o4;
  if (obf) {
    ushort4 u; u.x = f2bf(o4.x); u.y = f2bf(o4.y); u.z = f2bf(o4.z); u.w = f2bf(o4.w);
    ((ushort4*)(obf + (size_t)t * DM))[tid] = u;
  }
}

// ---------------- transpose f32->f32 and f32->bf16 ----------------
__global__ void k_tcvtf(const float* __restrict__ src, float* __restrict__ dst, int K, int N) {
  __shared__ float t[32][33];
  int k0 = blockIdx.x * 32, n0 = blockIdx.y * 32;
  int tx = threadIdx.x, ty = threadIdx.y;
  #pragma unroll
  for (int i = 0; i < 4; i++) t[ty + 8*i][tx] = src[(size_t)(k0 + ty + 8*i) * N + n0 + tx];
  __syncthreads();
  #pragma unroll
  for (int i = 0; i < 4; i++) dst[(size_t)(n0 + ty + 8*i) * K + k0 + tx] = t[tx][ty + 8*i];
}

__global__ void k_tcvt(const float* __restrict__ src, u16* __restrict__ dst, int K, int N) {
  __shared__ float t[32][33];
  size_t zoff = (size_t)blockIdx.z * K * N;
  src += zoff;
  u16* d = dst + zoff;
  int k0 = blockIdx.x * 32, n0 = blockIdx.y * 32;
  int tx = threadIdx.x, ty = threadIdx.y;
  #pragma unroll
  for (int i = 0; i < 4; i++) t[ty + 8*i][tx] = src[(size_t)(k0 + ty + 8*i) * N + n0 + tx];
  __syncthreads();
  int u = ty * 32 + tx;
  int r = u >> 3;            // output row (n offset)
  int kq = u & 7;            // k quad
  ushort4 o;
  o.x = f2bf(t[kq*4+0][r]); o.y = f2bf(t[kq*4+1][r]);
  o.z = f2bf(t[kq*4+2][r]); o.w = f2bf(t[kq*4+3][r]);
  *(ushort4*)&d[(size_t)(n0 + r) * K + k0 + kq*4] = o;
}

// ---------------- fp32 vector 64x64 TN GEMM (attention path: router exactness) ----------------
constexpr int FOP_PLAIN  = 0;
constexpr int FOP_VT     = 1;
constexpr int FOP_SCORES = 2;
constexpr int FOP_ATTO   = 3;
constexpr int FOP_PROJ   = 4;

struct GemmFArgs {
  const float* A; const float* B; float* C;
  const float* bias; const float* resid; const float* pos;
  int lda, ldb, ldc, K;
};

template<int OP>
__launch_bounds__(256)
__global__ void gemm_f(GemmFArgs p) {
  int bx = blockIdx.x, by = blockIdx.y, z = blockIdx.z;
  if constexpr (OP == FOP_SCORES) { if (by > bx) return; }
  const float *Abase, *Bbase;
  if constexpr (OP == FOP_SCORES) {
    Abase = p.A + (size_t)(z >> 3) * 524288 + (z & 7) * 128;
    Bbase = p.B + (size_t)(z >> 3) * 524288 + (z & 7) * 128;
  } else if constexpr (OP == FOP_ATTO) {
    Abase = p.A + (size_t)z * 262144;
    Bbase = p.B + (size_t)z * 65536;
  } else { Abase = p.A; Bbase = p.B; }

  __shared__ float As[16][68], Bs[16][68];
  int tid = threadIdx.x;
  int sr = tid >> 2, sc = (tid & 3) * 4;
  int tx = tid & 15, ty = tid >> 4;

  float acc[4][4] = {};
  int kmax = p.K;
  if constexpr (OP == FOP_ATTO) { int lim = bx * 64 + 64; kmax = lim < p.K ? lim : p.K; }

  for (int k0 = 0; k0 < kmax; k0 += 16) {
    float4 av = *(const float4*)(Abase + (size_t)(bx * 64 + sr) * p.lda + k0 + sc);
    float4 bv = *(const float4*)(Bbase + (size_t)(by * 64 + sr) * p.ldb + k0 + sc);
    As[sc + 0][sr] = av.x; As[sc + 1][sr] = av.y; As[sc + 2][sr] = av.z; As[sc + 3][sr] = av.w;
    Bs[sc + 0][sr] = bv.x; Bs[sc + 1][sr] = bv.y; Bs[sc + 2][sr] = bv.z; Bs[sc + 3][sr] = bv.w;
    __syncthreads();
    #pragma unroll
    for (int k = 0; k < 16; ++k) {
      float4 a = *(const float4*)&As[k][ty * 4];
      float4 b = *(const float4*)&Bs[k][tx * 4];
      acc[0][0] += a.x * b.x; acc[0][1] += a.x * b.y; acc[0][2] += a.x * b.z; acc[0][3] += a.x * b.w;
      acc[1][0] += a.y * b.x; acc[1][1] += a.y * b.y; acc[1][2] += a.y * b.z; acc[1][3] += a.y * b.w;
      acc[2][0] += a.z * b.x; acc[2][1] += a.z * b.y; acc[2][2] += a.z * b.z; acc[2][3] += a.z * b.w;
      acc[3][0] += a.w * b.x; acc[3][1] += a.w * b.y; acc[3][2] += a.w * b.z; acc[3][3] += a.w * b.w;
    }
    __syncthreads();
  }

  #pragma unroll
  for (int i = 0; i < 4; ++i) {
    int m = bx * 64 + ty * 4 + i;
    #pragma unroll
    for (int j = 0; j < 4; ++j) {
      int n = by * 64 + tx * 4 + j;
      float v = acc[i][j];
      if constexpr (OP == FOP_PLAIN) {
        p.C[(size_t)m * p.ldc + n] = v;
      } else if constexpr (OP == FOP_VT) {
        p.C[(size_t)((m >> 9) * 8 + (n >> 7)) * 65536 + (size_t)(n & 127) * 512 + (m & 511)] = v;
      } else if constexpr (OP == FOP_SCORES) {
        p.C[(size_t)z * 262144 + (size_t)m * 512 + n] = v;
      } else if constexpr (OP == FOP_ATTO) {
        p.C[(size_t)(z >> 3) * 524288 + (size_t)m * 1024 + (z & 7) * 128 + n] = v;
      } else if constexpr (OP == FOP_PROJ) {
        size_t idx = (size_t)m * 1024 + n;
        p.C[idx] = v + p.bias[n] + p.resid[idx] + p.pos[(size_t)(m & 511) * 1024 + n];
      }
    }
  }
}

// ---------------- causal softmax, f32 in place ----------------
__global__ void k_softmax_f(float* __restrict__ scores) {
  int q = blockIdx.x, bh = blockIdx.y, tid = threadIdx.x;
  float* row = scores + ((size_t)bh * 512 + q) * 512;
  const float scale = 0.088388347648318447f; // 128^-0.5
  int j0 = tid * 2;
  float v0 = -1e30f, v1 = -1e30f;
  if (j0 <= q)     v0 = row[j0] * scale;
  if (j0 + 1 <= q) v1 = row[j0 + 1] * scale;
  float m = fmaxf(v0, v1);
  for (int o = 32; o; o >>= 1) m = fmaxf(m, __shfl_down(m, o));
  __shared__ float sm[4], ssum[4];
  if ((tid & 63) == 0) sm[tid >> 6] = m;
  __syncthreads();
  m = fmaxf(fmaxf(sm[0], sm[1]), fmaxf(sm[2], sm[3]));
  float p0 = (j0 <= q)     ? expf(v0 - m) : 0.f;
  float p1 = (j0 + 1 <= q) ? expf(v1 - m) : 0.f;
  float s = p0 + p1;
  for (int o = 32; o; o >>= 1) s += __shfl_down(s, o);
  if ((tid & 63) == 0) ssum[tid >> 6] = s;
  __syncthreads();
  s = ssum[0] + ssum[1] + ssum[2] + ssum[3];
  float inv = 1.f / s;
  row[j0]     = p0 * inv;
  row[j0 + 1] = p1 * inv;
}

// ---------------- bf16 MFMA 128x128 TN GEMM, 2-phase dbuf + XCD-chunked 1D grid ----------------
// BM=BN=128, BK=32; 4 waves x (4x4 frags of 16x16x32). Grid is 1-D; block id is
// remapped so each XCD (id%8 under round-robin dispatch) owns a contiguous
// partition with operand-panel reuse inside its private L2.
constexpr int OP_MOE1 = 0; // gathered A rows, bf16 C=relu(acc+b1[e]); 2304 blocks, 4 cols/XCD
constexpr int OP_MOE2 = 1; // contiguous A rows, f32 C=acc+b2[e]; 576 blocks, 9 rows/XCD

struct GemmArgs {
  const u16* A; const u16* B; void* C;
  const float* bias;
  const int* joblist; const int* seg;
  int lda, ldb, K;
};

template<int OP>
__launch_bounds__(256)
__global__ void gemm_k(GemmArgs p) {
  int bid = blockIdx.x;
  int xcd = bid & 7, slot = bid >> 3;
  int bx, by;
  if constexpr (OP == OP_MOE1) {
    // 2304 blocks: XCD c -> by in [4c,4c+4), bx 0..71; by fastest (B-panel L2-hot)
    by = xcd * 4 + (slot & 3);
    bx = slot >> 2;
  } else {
    // 576 blocks: XCD c -> bx in [9c,9c+9), by 0..7; by fastest (A-panel L2-hot)
    bx = xcd * 9 + (slot >> 3);
    by = slot & 7;
  }
  int r0g = bx * 128;                      // global padded row of this tile
  if (r0g >= p.seg[8]) return;
  int z = 0;
  #pragma unroll
  for (int e = 1; e < 8; ++e) z += (r0g >= p.seg[e]) ? 1 : 0;
  const u16* Bbase = p.B + (size_t)z * 4194304;

  __shared__ __align__(16) u16 As[2 * 4096];
  __shared__ __align__(16) u16 Bs[2 * 4096];

  int tid = threadIdx.x;
  int lane = tid & 63, wid = tid >> 6;

  int srow = wid * 16 + (lane >> 2);
  int skoff = (lane & 3) * 8;

  const u16 *aptr0, *aptr1;
  if constexpr (OP == OP_MOE1) {
    int j0 = p.joblist[r0g + srow];
    int j1 = p.joblist[r0g + 64 + srow];
    aptr0 = p.A + (size_t)(j0 < 0 ? 0 : j0) * p.lda + skoff;
    aptr1 = p.A + (size_t)(j1 < 0 ? 0 : j1) * p.lda + skoff;
  } else {
    aptr0 = p.A + (size_t)(r0g + srow) * p.lda + skoff;
    aptr1 = p.A + (size_t)(r0g + 64 + srow) * p.lda + skoff;
  }
  const u16* bptr0 = Bbase + (size_t)(by * 128 + srow) * p.ldb + skoff;
  const u16* bptr1 = Bbase + (size_t)(by * 128 + 64 + srow) * p.ldb + skoff;

  int lo0 = (wid * 16) * 32;        // LDS chunk offsets (u16 units)
  int lo1 = ((wid + 4) * 16) * 32;

  int wr = wid >> 1, wc = wid & 1;
  int fm = lane & 15;
  int fk = (lane >> 4) * 8;

  f32x4 acc[4][4] = {};
  int nt = p.K >> 5;

  // prologue: stage tile 0 into buf 0
  gl_lds16(aptr0, &As[lo0]); gl_lds16(aptr1, &As[lo1]);
  gl_lds16(bptr0, &Bs[lo0]); gl_lds16(bptr1, &Bs[lo1]);
  __syncthreads();

  int cur = 0;
  for (int t = 0; t < nt; ++t) {
    if (t + 1 < nt) {                   // issue NEXT tile first (hides under MFMA)
      int nxt = (cur ^ 1) * 4096;
      int k0 = (t + 1) * 32;
      gl_lds16(aptr0 + k0, &As[nxt + lo0]); gl_lds16(aptr1 + k0, &As[nxt + lo1]);
      gl_lds16(bptr0 + k0, &Bs[nxt + lo0]); gl_lds16(bptr1 + k0, &Bs[nxt + lo1]);
    }
    int cb = cur * 4096;
    bf16x8 af[4], bfr[4];
    #pragma unroll
    for (int i = 0; i < 4; ++i) {
      af[i]  = *(const bf16x8*)&As[cb + (wr * 64 + i * 16 + fm) * 32 + fk];
      bfr[i] = *(const bf16x8*)&Bs[cb + (wc * 64 + i * 16 + fm) * 32 + fk];
    }
    #pragma unroll
    for (int mi = 0; mi < 4; ++mi)
      #pragma unroll
      for (int ni = 0; ni < 4; ++ni)
        acc[mi][ni] = __builtin_amdgcn_mfma_f32_16x16x32_bf16(af[mi], bfr[ni], acc[mi][ni], 0, 0, 0);
    __syncthreads();                    // drains vmcnt(0): next buf staged & this buf's reads done
    cur ^= 1;
  }

  int rb = (lane >> 4) * 4;
  int cl = lane & 15;
  #pragma unroll
  for (int mi = 0; mi < 4; ++mi)
    #pragma unroll
    for (int ni = 0; ni < 4; ++ni)
      #pragma unroll
      for (int j = 0; j < 4; ++j) {
        int m = r0g + wr * 64 + mi * 16 + rb + j;       // global padded row
        int n = by * 128 + wc * 64 + ni * 16 + cl;
        float v = acc[mi][ni][j];
        if constexpr (OP == OP_MOE1) {
          float t2 = v + p.bias[(size_t)z * FF + n];
          t2 = t2 > 0.f ? t2 : 0.f;
          ((u16*)p.C)[(size_t)m * FF + n] = f2bf(t2);
        } else {
          ((float*)p.C)[(size_t)m * DM + n] = v + p.bias[(size_t)z * DM + n];
        }
      }
}

// ---------------- router: inline fp32 LN + logits + noisy top-2 + gates ----------------
__global__ void k_router(const float* __restrict__ xin, const float* __restrict__ g,
                         const float* __restrict__ be,
                         const float* __restrict__ Wr, const float* __restrict__ br,
                         const float* __restrict__ Wn, const float* __restrict__ bn,
                         const float* __restrict__ noise,
                         float* __restrict__ gates, int* __restrict__ topidx) {
  int t = blockIdx.x, tid = threadIdx.x;
  float4 v = ((const float4*)(xin + (size_t)t * DM))[tid];
  float s = v.x + v.y + v.z + v.w;
  float sq = v.x*v.x + v.y*v.y + v.z*v.z + v.w*v.w;
  for (int o = 32; o; o >>= 1) { s += __shfl_down(s, o); sq += __shfl_down(sq, o); }
  __shared__ float ss[4], sqs[4];
  if ((tid & 63) == 0) { ss[tid >> 6] = s; sqs[tid >> 6] = sq; }
  __syncthreads();
  s  = ss[0] + ss[1] + ss[2] + ss[3];
  sq = sqs[0] + sqs[1] + sqs[2] + sqs[3];
  float mean = s * (1.f / DM);
  float var  = sq * (1.f / DM) - mean * mean;
  float rstd = rsqrtf(var + 1e-5f);
  float4 gg = ((const float4*)g)[tid];
  float4 bb = ((const float4*)be)[tid];
  float xl[4];
  xl[0] = (v.x - mean) * rstd * gg.x + bb.x;
  xl[1] = (v.y - mean) * rstd * gg.y + bb.y;
  xl[2] = (v.z - mean) * rstd * gg.z + bb.z;
  xl[3] = (v.w - mean) * rstd * gg.w + bb.w;
  float pl[8], pn[8];
  #pragma unroll
  for (int e = 0; e < 8; e++) { pl[e] = 0.f; pn[e] = 0.f; }
  #pragma unroll
  for (int j = 0; j < 4; j++) {
    int d = tid * 4 + j;
    float xv = xl[j];
    const float4* wr = (const float4*)(Wr + (size_t)d * 8);
    const float4* wn = (const float4*)(Wn + (size_t)d * 8);
    float4 a0 = wr[0], a1 = wr[1], c0 = wn[0], c1 = wn[1];
    pl[0] += xv * a0.x; pl[1] += xv * a0.y; pl[2] += xv * a0.z; pl[3] += xv * a0.w;
    pl[4] += xv * a1.x; pl[5] += xv * a1.y; pl[6] += xv * a1.z; pl[7] += xv * a1.w;
    pn[0] += xv * c0.x; pn[1] += xv * c0.y; pn[2] += xv * c0.z; pn[3] += xv * c0.w;
    pn[4] += xv * c1.x; pn[5] += xv * c1.y; pn[6] += xv * c1.z; pn[7] += xv * c1.w;
  }
  for (int o = 32; o; o >>= 1) {
    #pragma unroll
    for (int e = 0; e < 8; e++) { pl[e] += __shfl_down(pl[e], o); pn[e] += __shfl_down(pn[e], o); }
  }
  __shared__ float sl[4][8], sn[4][8];
  if ((tid & 63) == 0) {
    int w = tid >> 6;
    #pragma unroll
    for (int e = 0; e < 8; e++) { sl[w][e] = pl[e]; sn[w][e] = pn[e]; }
  }
  __syncthreads();
  if (tid == 0) {
    float noisy[8];
    #pragma unroll
    for (int e = 0; e < 8; e++) {
      float l  = sl[0][e] + sl[1][e] + sl[2][e] + sl[3][e] + br[e];
      float nn = sn[0][e] + sn[1][e] + sn[2][e] + sn[3][e] + bn[e];
      float sp = (nn > 20.f) ? nn : log1pf(expf(nn));
      noisy[e] = l + noise[(size_t)t * 8 + e] * sp;
    }
    int i0 = 0;
    for (int e = 1; e < 8; e++) if (noisy[e] > noisy[i0]) i0 = e;
    int i1 = (i0 == 0) ? 1 : 0;
    for (int e = 0; e < 8; e++) if (e != i0 && noisy[e] > noisy[i1]) i1 = e;
    float e1 = expf(noisy[i1] - noisy[i0]);
    float zz = 1.f + e1;
    gates[t * 2] = 1.f / zz; gates[t * 2 + 1] = e1 / zz;
    topidx[t * 2] = i0; topidx[t * 2 + 1] = i1;
  }
}

// ---------------- MoE bookkeeping ----------------
__global__ void k_moe_init(int* cnt, int* cnt2, int* joblist) {
  int i = blockIdx.x * 256 + threadIdx.x;
  if (i < JOBCAP) joblist[i] = -1;
  if (i < 8) { cnt[i] = 0; cnt2[i] = 0; }
}
__global__ void k_moe_count(const int* __restrict__ topidx, int* __restrict__ cnt) {
  int t = blockIdx.x * 256 + threadIdx.x;
  if (t >= TOK) return;
  atomicAdd(&cnt[topidx[t * 2]], 1);
  atomicAdd(&cnt[topidx[t * 2 + 1]], 1);
}
__global__ void k_moe_offsets(const int* __restrict__ cnt, int* __restrict__ seg) {
  if (threadIdx.x == 0) {
    int o = 0;
    for (int e = 0; e < 8; e++) { seg[e] = o; o += (cnt[e] + 127) & ~127; }  // pad to BM=128
    seg[8] = o;
  }
}
__global__ void k_moe_scatter(const int* __restrict__ topidx, int* __restrict__ cnt2,
                              const int* __restrict__ seg, int* __restrict__ joblist,
                              int* __restrict__ tokpos) {
  int t = blockIdx.x * 256 + threadIdx.x;
  if (t >= TOK) return;
  #pragma unroll
  for (int s = 0; s < 2; s++) {
    int e = topidx[t * 2 + s];
    int p = atomicAdd(&cnt2[e], 1);
    int pos = seg[e] + p;
    joblist[pos] = t;
    tokpos[t * 2 + s] = pos;
  }
}
__global__ void k_combine(const float* __restrict__ y, const float* __restrict__ gates,
                          const int* __restrict__ tokpos, float* __restrict__ out) {
  int t = blockIdx.x, tid = threadIdx.x;
  int p0 = tokpos[t * 2], p1 = tokpos[t * 2 + 1];
  float g0 = gates[t * 2], g1 = gates[t * 2 + 1];
  float4 a = ((const float4*)(y + (size_t)p0 * DM))[tid];
  float4 b = ((const float4*)(y + (size_t)p1 * DM))[tid];
  float4 o;
  o.x = g0 * a.x + g1 * b.x; o.y = g0 * a.y + g1 * b.y;
  o.z = g0 * a.z + g1 * b.z; o.w = g0 * a.w + g1 * b.w;
  ((float4*)(out + (size_t)t * DM))[tid] = o;
}

// ---------------- feature mean + classifier ----------------
__global__ void k_feature(const float* __restrict__ second, float* __restrict__ feat) {
  int i = blockIdx.x * 256 + threadIdx.x;
  if (i >= 8 * DM) return;
  int b = i >> 10, d = i & 1023;
  const float* p = second + (size_t)b * SEQ * DM + d;
  float s = 0.f;
  for (int j = 0; j < SEQ; j++) s += p[(size_t)j * DM];
  feat[i] = s * (1.f / SEQ);
}
__global__ void k_cls(const float* __restrict__ feat, const float* __restrict__ Wc,
                      const float* __restrict__ bc, float* __restrict__ cls) {
  int o = blockIdx.x; int b = o / 10, n = o % 10; int l = threadIdx.x;
  float s = 0.f;
  for (int d = l; d < DM; d += 64) s += feat[b * DM + d] * Wc[(size_t)d * 10 + n];
  for (int off = 32; off; off >>= 1) s += __shfl_down(s, off);
  if (l == 0) cls[o] = s + bc[n];
}

// ---------------- launch ----------------
extern "C" void kernel_launch(void* const* d_in, const int* in_sizes, int n_in,
                              void* d_out, int out_size, void* d_ws, size_t ws_size,
                              hipStream_t stream) {
  const int*   ids    = (const int*)d_in[0];
  const float* emb    = (const float*)d_in[2];
  const float* pos    = (const float*)d_in[3];
  const float* Wq     = (const float*)d_in[4];
  const float* Wk     = (const float*)d_in[5];
  const float* Wv     = (const float*)d_in[6];
  const float* Wo     = (const float*)d_in[7];
  const float* bo     = (const float*)d_in[8];
  const float* g1     = (const float*)d_in[9];
  const float* be1    = (const float*)d_in[10];
  const float* g2     = (const float*)d_in[11];
  const float* be2    = (const float*)d_in[12];
  const float* g3     = (const float*)d_in[13];
  const float* be3    = (const float*)d_in[14];
  const float* Wr1    = (const float*)d_in[15];
  const float* br1    = (const float*)d_in[16];
  const float* Wn1    = (const float*)d_in[17];
  const float* bn1    = (const float*)d_in[18];
  const float* W1a    = (const float*)d_in[19];
  const float* b1a    = (const float*)d_in[20];
  const float* W2a    = (const float*)d_in[21];
  const float* b2a    = (const float*)d_in[22];
  const float* Wr2    = (const float*)d_in[23];
  const float* br2    = (const float*)d_in[24];
  const float* Wn2    = (const float*)d_in[25];
  const float* bn2    = (const float*)d_in[26];
  const float* W1b    = (const float*)d_in[27];
  const float* b1b    = (const float*)d_in[28];
  const float* W2b    = (const float*)d_in[29];
  const float* b2b    = (const float*)d_in[30];
  const float* noise1 = (const float*)d_in[31];
  const float* noise2 = (const float*)d_in[32];
  const float* Wc     = (const float*)d_in[33];
  const float* bc     = (const float*)d_in[34];

  char* wsp = (char*)d_ws; size_t off = 0;
  auto alloc = [&](size_t bytes) -> void* {
    void* p = wsp + off; off += (bytes + 255) & ~(size_t)255; return p;
  };
  // ---- workspace (~223 MB; ws_size >= 448MB per round-1 evidence) ----
  char*  G     = (char*)alloc(180355072);              // phase-overlaid big region
  float* x     = (float*)alloc((size_t)TOK * DM * 4);
  float* x2    = (float*)alloc((size_t)TOK * DM * 4);
  u16*   xlnb  = (u16*)alloc((size_t)TOK * DM * 2);
  float* gates  = (float*)alloc(TOK * 2 * 4);
  int*   topidx = (int*)alloc(TOK * 2 * 4);
  int*   cnt    = (int*)alloc(8 * 4);
  int*   cnt2   = (int*)alloc(8 * 4);
  int*   seg    = (int*)alloc(16 * 4);
  int*   joblist= (int*)alloc(JOBCAP * 4);
  int*   tokpos = (int*)alloc(TOK * 2 * 4);
  (void)ws_size; (void)in_sizes; (void)n_in; (void)out_size;

  // attention-phase views (151MB)
  float* WQT  = (float*)(G + 0);
  float* WKT  = (float*)(G + 4194304);
  float* WVT  = (float*)(G + 8388608);
  float* WOT  = (float*)(G + 12582912);
  float* QB   = (float*)(G + 16777216);   // q; reused as o
  float* KB   = (float*)(G + 33554432);
  float* VT   = (float*)(G + 50331648);   // [b][h][d][s]
  float* SC   = (float*)(G + 67108864);   // scores/att f32 [64][512][512]
  float* XLNF = (float*)(G + 134217728);
  // moe-phase views (180MB)
  u16*   H    = (u16*)(G + 0);            // [9216][4096] bf16
  float* Y    = (float*)(G + 75497472);   // [9216][1024] f32
  u16*   WBUF = (u16*)(G + 113246208);    // expert weights bf16, reused W1->W2

  float* out_first  = (float*)d_out;
  float* out_second = out_first + (size_t)TOK * DM;
  float* feat       = out_first + (size_t)2 * TOK * DM;
  float* cls        = feat + 8 * DM;

  dim3 tb(32, 8);
  // ---- attention phase (pure fp32: router input must match numpy to ~1e-6) ----
  hipLaunchKernelGGL(k_tcvtf, dim3(32, 32, 1), tb, 0, stream, Wq, WQT, DM, DM);
  hipLaunchKernelGGL(k_tcvtf, dim3(32, 32, 1), tb, 0, stream, Wk, WKT, DM, DM);
  hipLaunchKernelGGL(k_tcvtf, dim3(32, 32, 1), tb, 0, stream, Wv, WVT, DM, DM);
  hipLaunchKernelGGL(k_tcvtf, dim3(32, 32, 1), tb, 0, stream, Wo, WOT, DM, DM);
  hipLaunchKernelGGL(k_embed, dim3(TOK), dim3(256), 0, stream, ids, emb, x);
  hipLaunchKernelGGL(k_ln, dim3(TOK), dim3(256), 0, stream, x, g1, be1, XLNF, (u16*)nullptr);

  GemmFArgs a{};
  a.A = XLNF; a.B = WQT; a.C = QB; a.lda = DM; a.ldb = DM; a.ldc = DM; a.K = DM;
  hipLaunchKernelGGL(gemm_f<FOP_PLAIN>, dim3(64, 16, 1), dim3(256), 0, stream, a);
  a.B = WKT; a.C = KB;
  hipLaunchKernelGGL(gemm_f<FOP_PLAIN>, dim3(64, 16, 1), dim3(256), 0, stream, a);
  a.B = WVT; a.C = VT;
  hipLaunchKernelGGL(gemm_f<FOP_VT>, dim3(64, 16, 1), dim3(256), 0, stream, a);

  GemmFArgs sg{};
  sg.A = QB; sg.B = KB; sg.C = SC; sg.lda = DM; sg.ldb = DM; sg.ldc = SEQ; sg.K = HD;
  hipLaunchKernelGGL(gemm_f<FOP_SCORES>, dim3(8, 8, 64), dim3(256), 0, stream, sg);
  hipLaunchKernelGGL(k_softmax_f, dim3(SEQ, 64), dim3(256), 0, stream, SC);

  GemmFArgs og{};
  og.A = SC; og.B = VT; og.C = QB;
  og.lda = SEQ; og.ldb = SEQ; og.ldc = DM; og.K = SEQ;
  hipLaunchKernelGGL(gemm_f<FOP_ATTO>, dim3(8, 2, 64), dim3(256), 0, stream, og);

  GemmFArgs pg{};
  pg.A = QB; pg.B = WOT; pg.C = x2; pg.bias = bo; pg.resid = x; pg.pos = pos;
  pg.lda = DM; pg.ldb = DM; pg.ldc = DM; pg.K = DM;
  hipLaunchKernelGGL(gemm_f<FOP_PROJ>, dim3(64, 16, 1), dim3(256), 0, stream, pg);

  // ---- MoE phase (bf16 MFMA experts; router fp32) ----
  auto run_moe = [&](const float* g, const float* be, const float* Wr, const float* br,
                     const float* Wn, const float* bn, const float* noise,
                     const float* W1, const float* b1, const float* W2, const float* b2,
                     float* outp) {
    hipLaunchKernelGGL(k_ln, dim3(TOK), dim3(256), 0, stream, x2, g, be, (float*)nullptr, xlnb);
    hipLaunchKernelGGL(k_router, dim3(TOK), dim3(256), 0, stream, x2, g, be, Wr, br, Wn, bn, noise, gates, topidx);
    hipLaunchKernelGGL(k_moe_init, dim3(36), dim3(256), 0, stream, cnt, cnt2, joblist);
    hipLaunchKernelGGL(k_moe_count, dim3(16), dim3(256), 0, stream, topidx, cnt);
    hipLaunchKernelGGL(k_moe_offsets, dim3(1), dim3(64), 0, stream, cnt, seg);
    hipLaunchKernelGGL(k_moe_scatter, dim3(16), dim3(256), 0, stream, topidx, cnt2, seg, joblist, tokpos);
    hipLaunchKernelGGL(k_tcvt, dim3(32, 128, 8), tb, 0, stream, W1, WBUF, DM, FF);
    GemmArgs m1{};
    m1.A = xlnb; m1.B = WBUF; m1.C = H; m1.bias = b1; m1.joblist = joblist; m1.seg = seg;
    m1.lda = DM; m1.ldb = DM; m1.K = DM;
    hipLaunchKernelGGL(gemm_k<OP_MOE1>, dim3(2304), dim3(256), 0, stream, m1);
    hipLaunchKernelGGL(k_tcvt, dim3(128, 32, 8), tb, 0, stream, W2, WBUF, FF, DM);
    GemmArgs m2{};
    m2.A = H; m2.B = WBUF; m2.C = Y; m2.bias = b2; m2.seg = seg;
    m2.lda = FF; m2.ldb = FF; m2.K = FF;
    hipLaunchKernelGGL(gemm_k<OP_MOE2>, dim3(576), dim3(256), 0, stream, m2);
    hipLaunchKernelGGL(k_combine, dim3(TOK), dim3(256), 0, stream, Y, gates, tokpos, outp);
  };
  run_moe(g2, be2, Wr1, br1, Wn1, bn1, noise1, W1a, b1a, W2a, b2a, out_first);
  run_moe(g3, be3, Wr2, br2, Wn2, bn2, noise2, W1b, b1b, W2b, b2b, out_second);

  hipLaunchKernelGGL(k_feature, dim3(32), dim3(256), 0, stream, out_second, feat);
  hipLaunchKernelGGL(k_cls, dim3(80), dim3(64), 0, stream, feat, Wc, bc, cls);
}

// Round 8
// 1307.879 us; speedup vs baseline: 1.2547x; 1.2084x over previous
//
#include <hip/hip_runtime.h>
#include <cstdint>

typedef unsigned short u16;
typedef __attribute__((ext_vector_type(8))) __bf16 bf16x8;
typedef __attribute__((ext_vector_type(4))) float f32x4;

#define TOK 4096
#define DM  1024
#define EXP 8
#define FF  4096
#define SEQ 512
#define NH  8
#define HD  128
#define JOBCAP 9216

__device__ __forceinline__ u16 f2bf(float f) {
  union { float f; unsigned int u; } v; v.f = f;
  unsigned int u = v.u;
  u += 0x7FFFu + ((u >> 16) & 1u);   // round-to-nearest-even
  return (u16)(u >> 16);
}
__device__ __forceinline__ float bf2f(u16 h) {
  union { unsigned int u; float f; } v; v.u = ((unsigned int)h) << 16; return v.f;
}

// async global->LDS, 16B per lane; dest = wave-uniform base + lane*16
__device__ __forceinline__ void gl_lds16(const u16* g, u16* l) {
  __builtin_amdgcn_global_load_lds(
      (const __attribute__((address_space(1))) unsigned int*)g,
      (__attribute__((address_space(3))) unsigned int*)l, 16, 0, 0);
}

// ---------------- embed gather ----------------
__global__ void k_embed(const int* __restrict__ ids, const float* __restrict__ emb,
                        float* __restrict__ x) {
  int t = blockIdx.x;
  int id = ids[t];
  const float4* src = (const float4*)(emb + (size_t)id * DM);
  float4* dst = (float4*)(x + (size_t)t * DM);
  dst[threadIdx.x] = src[threadIdx.x];
}

// ---------------- layernorm -> bf16 (MoE path) ----------------
__global__ void k_ln(const float* __restrict__ in, const float* __restrict__ g,
                     const float* __restrict__ be, u16* __restrict__ obf) {
  int t = blockIdx.x, tid = threadIdx.x;
  float4 v = ((const float4*)(in + (size_t)t * DM))[tid];
  float s = v.x + v.y + v.z + v.w;
  float sq = v.x*v.x + v.y*v.y + v.z*v.z + v.w*v.w;
  for (int o = 32; o; o >>= 1) { s += __shfl_down(s, o); sq += __shfl_down(sq, o); }
  __shared__ float ss[4], sqs[4];
  if ((tid & 63) == 0) { ss[tid >> 6] = s; sqs[tid >> 6] = sq; }
  __syncthreads();
  s  = ss[0] + ss[1] + ss[2] + ss[3];
  sq = sqs[0] + sqs[1] + sqs[2] + sqs[3];
  float mean = s * (1.f / DM);
  float var  = sq * (1.f / DM) - mean * mean;
  float rstd = rsqrtf(var + 1e-5f);
  float4 gg = ((const float4*)g)[tid];
  float4 bb = ((const float4*)be)[tid];
  ushort4 u;
  u.x = f2bf((v.x - mean) * rstd * gg.x + bb.x);
  u.y = f2bf((v.y - mean) * rstd * gg.y + bb.y);
  u.z = f2bf((v.z - mean) * rstd * gg.z + bb.z);
  u.w = f2bf((v.w - mean) * rstd * gg.w + bb.w);
  ((ushort4*)(obf + (size_t)t * DM))[tid] = u;
}

// ---------------- layernorm -> hi/lo bf16 pair (attention path) ----------------
__global__ void k_ln2(const float* __restrict__ in, const float* __restrict__ g,
                      const float* __restrict__ be, u16* __restrict__ oh,
                      u16* __restrict__ ol) {
  int t = blockIdx.x, tid = threadIdx.x;
  float4 v = ((const float4*)(in + (size_t)t * DM))[tid];
  float s = v.x + v.y + v.z + v.w;
  float sq = v.x*v.x + v.y*v.y + v.z*v.z + v.w*v.w;
  for (int o = 32; o; o >>= 1) { s += __shfl_down(s, o); sq += __shfl_down(sq, o); }
  __shared__ float ss[4], sqs[4];
  if ((tid & 63) == 0) { ss[tid >> 6] = s; sqs[tid >> 6] = sq; }
  __syncthreads();
  s  = ss[0] + ss[1] + ss[2] + ss[3];
  sq = sqs[0] + sqs[1] + sqs[2] + sqs[3];
  float mean = s * (1.f / DM);
  float var  = sq * (1.f / DM) - mean * mean;
  float rstd = rsqrtf(var + 1e-5f);
  float4 gg = ((const float4*)g)[tid];
  float4 bb = ((const float4*)be)[tid];
  float o4[4];
  o4[0] = (v.x - mean) * rstd * gg.x + bb.x;
  o4[1] = (v.y - mean) * rstd * gg.y + bb.y;
  o4[2] = (v.z - mean) * rstd * gg.z + bb.z;
  o4[3] = (v.w - mean) * rstd * gg.w + bb.w;
  ushort4 uh, ul;
  u16* ph = (u16*)&uh; u16* pl = (u16*)&ul;
  #pragma unroll
  for (int i = 0; i < 4; i++) {
    u16 hi = f2bf(o4[i]); ph[i] = hi; pl[i] = f2bf(o4[i] - bf2f(hi));
  }
  ((ushort4*)(oh + (size_t)t * DM))[tid] = uh;
  ((ushort4*)(ol + (size_t)t * DM))[tid] = ul;
}

// ---------------- transpose f32 [K,N] -> hi/lo bf16 [N,K] ----------------
__global__ void k_tcvt_split(const float* __restrict__ src, u16* __restrict__ dh,
                             u16* __restrict__ dl, int K, int N) {
  __shared__ float t[32][33];
  int k0 = blockIdx.x * 32, n0 = blockIdx.y * 32;
  int tx = threadIdx.x, ty = threadIdx.y;
  #pragma unroll
  for (int i = 0; i < 4; i++) t[ty + 8*i][tx] = src[(size_t)(k0 + ty + 8*i) * N + n0 + tx];
  __syncthreads();
  int u = ty * 32 + tx;
  int r = u >> 3, kq = u & 7;
  ushort4 oh, ol;
  u16* ph = (u16*)&oh; u16* pl = (u16*)&ol;
  #pragma unroll
  for (int i = 0; i < 4; i++) {
    float v = t[kq*4+i][r];
    u16 hi = f2bf(v); ph[i] = hi; pl[i] = f2bf(v - bf2f(hi));
  }
  *(ushort4*)&dh[(size_t)(n0 + r) * K + k0 + kq*4] = oh;
  *(ushort4*)&dl[(size_t)(n0 + r) * K + k0 + kq*4] = ol;
}

// ---------------- transpose f32 [K,N] -> bf16 [N,K], z-batched (MoE weights) ----------------
__global__ void k_tcvt(const float* __restrict__ src, u16* __restrict__ dst, int K, int N) {
  __shared__ float t[32][33];
  size_t zoff = (size_t)blockIdx.z * K * N;
  src += zoff;
  u16* d = dst + zoff;
  int k0 = blockIdx.x * 32, n0 = blockIdx.y * 32;
  int tx = threadIdx.x, ty = threadIdx.y;
  #pragma unroll
  for (int i = 0; i < 4; i++) t[ty + 8*i][tx] = src[(size_t)(k0 + ty + 8*i) * N + n0 + tx];
  __syncthreads();
  int u = ty * 32 + tx;
  int r = u >> 3, kq = u & 7;
  ushort4 o;
  o.x = f2bf(t[kq*4+0][r]); o.y = f2bf(t[kq*4+1][r]);
  o.z = f2bf(t[kq*4+2][r]); o.w = f2bf(t[kq*4+3][r]);
  *(ushort4*)&d[(size_t)(n0 + r) * K + k0 + kq*4] = o;
}

// ---------------- causal softmax f32 -> att hi/lo bf16 in place ----------------
// Row layout after: u16[0..511]=hi, u16[512..1023]=lo (over the same 2KB f32 row).
// All f32 reads happen before barrier 1; u16 writes after barrier 2 -> race-free.
__global__ void k_softmax_h(float* __restrict__ scores) {
  int q = blockIdx.x, bh = blockIdx.y, tid = threadIdx.x;
  float* row = scores + ((size_t)bh * 512 + q) * 512;
  u16* orow = (u16*)row;
  const float scale = 0.088388347648318447f; // 128^-0.5
  int j0 = tid * 2;
  float v0 = -1e30f, v1 = -1e30f;
  if (j0 <= q)     v0 = row[j0] * scale;
  if (j0 + 1 <= q) v1 = row[j0 + 1] * scale;
  float m = fmaxf(v0, v1);
  for (int o = 32; o; o >>= 1) m = fmaxf(m, __shfl_down(m, o));
  __shared__ float sm[4], ssum[4];
  if ((tid & 63) == 0) sm[tid >> 6] = m;
  __syncthreads();
  m = fmaxf(fmaxf(sm[0], sm[1]), fmaxf(sm[2], sm[3]));
  float p0 = (j0 <= q)     ? expf(v0 - m) : 0.f;
  float p1 = (j0 + 1 <= q) ? expf(v1 - m) : 0.f;
  float s = p0 + p1;
  for (int o = 32; o; o >>= 1) s += __shfl_down(s, o);
  if ((tid & 63) == 0) ssum[tid >> 6] = s;
  __syncthreads();
  s = ssum[0] + ssum[1] + ssum[2] + ssum[3];
  float inv = 1.f / s;
  float pi0 = p0 * inv, pi1 = p1 * inv;
  u16 h0 = f2bf(pi0), h1 = f2bf(pi1);
  orow[j0]       = h0; orow[j0 + 1]       = h1;
  orow[512 + j0] = f2bf(pi0 - bf2f(h0));
  orow[512 + j0 + 1] = f2bf(pi1 - bf2f(h1));
}

// ---------------- split-bf16 4-pass MFMA GEMM (attention path, fp32-class accuracy) ----------------
// C = Ah*Bh + Ah*Bl + Al*Bh + Al*Bl, each pass a 128x128/BK32 2-phase dbuf loop.
constexpr int HOP_QKV    = 0; // A=xln, B=[Wq;Wk;Wv]^T, N=3072 -> Q/K hi/lo + VT hi/lo
constexpr int HOP_SCORES = 1; // per (b,h): Q.K^T -> f32 scores, causal tile skip
constexpr int HOP_PV     = 2; // att(hi/lo interleaved rows) x VT -> O hi/lo, causal k-limit
constexpr int HOP_PROJ   = 3; // O x Wo^T + bias + resid + pos -> f32 x2

struct GemmHArgs {
  const u16 *Ah, *Al, *Bh, *Bl;
  u16 *D0h, *D0l, *D1h, *D1l, *D2h, *D2l;
  float *Cf;
  const float *bias, *resid, *pos;
  int lda, ldb, K;
};

template<int OP>
__launch_bounds__(256)
__global__ void gemm_h(GemmHArgs p) {
  int bx, by, z = blockIdx.z;
  if constexpr (OP == HOP_QKV) {         // 768 blocks: XCD c -> by in [3c,3c+3), bx fastest
    int bid = blockIdx.x; int xcd = bid & 7, slot = bid >> 3;
    by = xcd * 3 + (slot >> 5); bx = slot & 31;
  } else if constexpr (OP == HOP_PROJ) { // 256 blocks: XCD c -> by=c, bx fastest
    int bid = blockIdx.x; by = bid & 7; bx = bid >> 3;
  } else {
    bx = blockIdx.x; by = blockIdx.y;
    if constexpr (OP == HOP_SCORES) { if (by > bx) return; }
  }

  const u16 *Ahb, *Alb, *Bhb, *Blb;
  if constexpr (OP == HOP_SCORES) {
    size_t off = (size_t)(z >> 3) * 524288 + (size_t)(z & 7) * 128;
    Ahb = p.Ah + off; Alb = p.Al + off; Bhb = p.Bh + off; Blb = p.Bl + off;
  } else if constexpr (OP == HOP_PV) {
    size_t aoff = (size_t)z * 524288;      // att u16 view [z][512][1024]
    Ahb = p.Ah + aoff; Alb = p.Ah + aoff + 512;
    size_t boff = (size_t)z * 65536;       // VT [z][128][512]
    Bhb = p.Bh + boff; Blb = p.Bl + boff;
  } else {
    Ahb = p.Ah; Alb = p.Al; Bhb = p.Bh; Blb = p.Bl;
  }

  int kmax = p.K;
  if constexpr (OP == HOP_PV) { int lim = bx * 128 + 128; kmax = lim < p.K ? lim : p.K; }
  int nt = kmax >> 5;

  __shared__ __align__(16) u16 As[2 * 4096];
  __shared__ __align__(16) u16 Bs[2 * 4096];

  int tid = threadIdx.x, lane = tid & 63, wid = tid >> 6;
  int srow = wid * 16 + (lane >> 2), skoff = (lane & 3) * 8;
  int lo0 = (wid * 16) * 32, lo1 = ((wid + 4) * 16) * 32;
  int wr = wid >> 1, wc = wid & 1, fm = lane & 15, fk = (lane >> 4) * 8;

  f32x4 acc[4][4] = {};
  const size_t lda = p.lda, ldb = p.ldb;

  #pragma unroll 1
  for (int pass = 0; pass < 4; ++pass) {
    const u16* Ab = (pass < 2) ? Ahb : Alb;
    const u16* Bb = (pass & 1) ? Blb : Bhb;
    const u16* aptr0 = Ab + (size_t)(bx * 128 + srow) * lda + skoff;
    const u16* aptr1 = Ab + (size_t)(bx * 128 + 64 + srow) * lda + skoff;
    const u16* bptr0 = Bb + (size_t)(by * 128 + srow) * ldb + skoff;
    const u16* bptr1 = Bb + (size_t)(by * 128 + 64 + srow) * ldb + skoff;

    gl_lds16(aptr0, &As[lo0]); gl_lds16(aptr1, &As[lo1]);
    gl_lds16(bptr0, &Bs[lo0]); gl_lds16(bptr1, &Bs[lo1]);
    __syncthreads();
    int cur = 0;
    for (int t = 0; t < nt; ++t) {
      if (t + 1 < nt) {
        int nxt = (cur ^ 1) * 4096;
        int k0 = (t + 1) * 32;
        gl_lds16(aptr0 + k0, &As[nxt + lo0]); gl_lds16(aptr1 + k0, &As[nxt + lo1]);
        gl_lds16(bptr0 + k0, &Bs[nxt + lo0]); gl_lds16(bptr1 + k0, &Bs[nxt + lo1]);
      }
      int cb = cur * 4096;
      bf16x8 af[4], bfr[4];
      #pragma unroll
      for (int i = 0; i < 4; ++i) {
        af[i]  = *(const bf16x8*)&As[cb + (wr * 64 + i * 16 + fm) * 32 + fk];
        bfr[i] = *(const bf16x8*)&Bs[cb + (wc * 64 + i * 16 + fm) * 32 + fk];
      }
      #pragma unroll
      for (int mi = 0; mi < 4; ++mi)
        #pragma unroll
        for (int ni = 0; ni < 4; ++ni)
          acc[mi][ni] = __builtin_amdgcn_mfma_f32_16x16x32_bf16(af[mi], bfr[ni], acc[mi][ni], 0, 0, 0);
      __syncthreads();
      cur ^= 1;
    }
  }

  int rb = (lane >> 4) * 4, cl = lane & 15;
  #pragma unroll
  for (int mi = 0; mi < 4; ++mi)
    #pragma unroll
    for (int ni = 0; ni < 4; ++ni)
      #pragma unroll
      for (int j = 0; j < 4; ++j) {
        int m = bx * 128 + wr * 64 + mi * 16 + rb + j;
        int n = by * 128 + wc * 64 + ni * 16 + cl;
        float v = acc[mi][ni][j];
        if constexpr (OP == HOP_QKV) {
          u16 hi = f2bf(v); u16 lo = f2bf(v - bf2f(hi));
          int sel = n >> 10, nn = n & 1023;
          if (sel == 0) {
            p.D0h[(size_t)m * DM + nn] = hi; p.D0l[(size_t)m * DM + nn] = lo;
          } else if (sel == 1) {
            p.D1h[(size_t)m * DM + nn] = hi; p.D1l[(size_t)m * DM + nn] = lo;
          } else {
            size_t idx = (size_t)((m >> 9) * 8 + (nn >> 7)) * 65536 + (size_t)(nn & 127) * 512 + (m & 511);
            p.D2h[idx] = hi; p.D2l[idx] = lo;
          }
        } else if constexpr (OP == HOP_SCORES) {
          p.Cf[(size_t)z * 262144 + (size_t)m * 512 + n] = v;
        } else if constexpr (OP == HOP_PV) {
          u16 hi = f2bf(v); u16 lo = f2bf(v - bf2f(hi));
          size_t idx = (size_t)(z >> 3) * 524288 + (size_t)m * 1024 + (size_t)(z & 7) * 128 + n;
          p.D0h[idx] = hi; p.D0l[idx] = lo;
        } else { // HOP_PROJ
          size_t idx = (size_t)m * 1024 + n;
          p.Cf[idx] = v + p.bias[n] + p.resid[idx] + p.pos[(size_t)(m & 511) * 1024 + n];
        }
      }
}

// ---------------- bf16 MFMA 128x128 TN GEMM, 2-phase dbuf + XCD-chunked 1D grid (MoE) ----------------
constexpr int OP_MOE1 = 0;
constexpr int OP_MOE2 = 1;

struct GemmArgs {
  const u16* A; const u16* B; void* C;
  const float* bias;
  const int* joblist; const int* seg;
  int lda, ldb, K;
};

template<int OP>
__launch_bounds__(256)
__global__ void gemm_k(GemmArgs p) {
  int bid = blockIdx.x;
  int xcd = bid & 7, slot = bid >> 3;
  int bx, by;
  if constexpr (OP == OP_MOE1) {
    by = xcd * 4 + (slot & 3);
    bx = slot >> 2;
  } else {
    bx = xcd * 9 + (slot >> 3);
    by = slot & 7;
  }
  int r0g = bx * 128;
  if (r0g >= p.seg[8]) return;
  int z = 0;
  #pragma unroll
  for (int e = 1; e < 8; ++e) z += (r0g >= p.seg[e]) ? 1 : 0;
  const u16* Bbase = p.B + (size_t)z * 4194304;

  __shared__ __align__(16) u16 As[2 * 4096];
  __shared__ __align__(16) u16 Bs[2 * 4096];

  int tid = threadIdx.x;
  int lane = tid & 63, wid = tid >> 6;

  int srow = wid * 16 + (lane >> 2);
  int skoff = (lane & 3) * 8;

  const u16 *aptr0, *aptr1;
  if constexpr (OP == OP_MOE1) {
    int j0 = p.joblist[r0g + srow];
    int j1 = p.joblist[r0g + 64 + srow];
    aptr0 = p.A + (size_t)(j0 < 0 ? 0 : j0) * p.lda + skoff;
    aptr1 = p.A + (size_t)(j1 < 0 ? 0 : j1) * p.lda + skoff;
  } else {
    aptr0 = p.A + (size_t)(r0g + srow) * p.lda + skoff;
    aptr1 = p.A + (size_t)(r0g + 64 + srow) * p.lda + skoff;
  }
  const u16* bptr0 = Bbase + (size_t)(by * 128 + srow) * p.ldb + skoff;
  const u16* bptr1 = Bbase + (size_t)(by * 128 + 64 + srow) * p.ldb + skoff;

  int lo0 = (wid * 16) * 32;
  int lo1 = ((wid + 4) * 16) * 32;

  int wr = wid >> 1, wc = wid & 1;
  int fm = lane & 15;
  int fk = (lane >> 4) * 8;

  f32x4 acc[4][4] = {};
  int nt = p.K >> 5;

  gl_lds16(aptr0, &As[lo0]); gl_lds16(aptr1, &As[lo1]);
  gl_lds16(bptr0, &Bs[lo0]); gl_lds16(bptr1, &Bs[lo1]);
  __syncthreads();

  int cur = 0;
  for (int t = 0; t < nt; ++t) {
    if (t + 1 < nt) {
      int nxt = (cur ^ 1) * 4096;
      int k0 = (t + 1) * 32;
      gl_lds16(aptr0 + k0, &As[nxt + lo0]); gl_lds16(aptr1 + k0, &As[nxt + lo1]);
      gl_lds16(bptr0 + k0, &Bs[nxt + lo0]); gl_lds16(bptr1 + k0, &Bs[nxt + lo1]);
    }
    int cb = cur * 4096;
    bf16x8 af[4], bfr[4];
    #pragma unroll
    for (int i = 0; i < 4; ++i) {
      af[i]  = *(const bf16x8*)&As[cb + (wr * 64 + i * 16 + fm) * 32 + fk];
      bfr[i] = *(const bf16x8*)&Bs[cb + (wc * 64 + i * 16 + fm) * 32 + fk];
    }
    #pragma unroll
    for (int mi = 0; mi < 4; ++mi)
      #pragma unroll
      for (int ni = 0; ni < 4; ++ni)
        acc[mi][ni] = __builtin_amdgcn_mfma_f32_16x16x32_bf16(af[mi], bfr[ni], acc[mi][ni], 0, 0, 0);
    __syncthreads();
    cur ^= 1;
  }

  int rb = (lane >> 4) * 4;
  int cl = lane & 15;
  #pragma unroll
  for (int mi = 0; mi < 4; ++mi)
    #pragma unroll
    for (int ni = 0; ni < 4; ++ni)
      #pragma unroll
      for (int j = 0; j < 4; ++j) {
        int m = r0g + wr * 64 + mi * 16 + rb + j;
        int n = by * 128 + wc * 64 + ni * 16 + cl;
        float v = acc[mi][ni][j];
        if constexpr (OP == OP_MOE1) {
          float t2 = v + p.bias[(size_t)z * FF + n];
          t2 = t2 > 0.f ? t2 : 0.f;
          ((u16*)p.C)[(size_t)m * FF + n] = f2bf(t2);
        } else {
          ((float*)p.C)[(size_t)m * DM + n] = v + p.bias[(size_t)z * DM + n];
        }
      }
}

// ---------------- router: inline fp32 LN + logits + noisy top-2 + gates ----------------
__global__ void k_router(const float* __restrict__ xin, const float* __restrict__ g,
                         const float* __restrict__ be,
                         const float* __restrict__ Wr, const float* __restrict__ br,
                         const float* __restrict__ Wn, const float* __restrict__ bn,
                         const float* __restrict__ noise,
                         float* __restrict__ gates, int* __restrict__ topidx) {
  int t = blockIdx.x, tid = threadIdx.x;
  float4 v = ((const float4*)(xin + (size_t)t * DM))[tid];
  float s = v.x + v.y + v.z + v.w;
  float sq = v.x*v.x + v.y*v.y + v.z*v.z + v.w*v.w;
  for (int o = 32; o; o >>= 1) { s += __shfl_down(s, o); sq += __shfl_down(sq, o); }
  __shared__ float ss[4], sqs[4];
  if ((tid & 63) == 0) { ss[tid >> 6] = s; sqs[tid >> 6] = sq; }
  __syncthreads();
  s  = ss[0] + ss[1] + ss[2] + ss[3];
  sq = sqs[0] + sqs[1] + sqs[2] + sqs[3];
  float mean = s * (1.f / DM);
  float var  = sq * (1.f / DM) - mean * mean;
  float rstd = rsqrtf(var + 1e-5f);
  float4 gg = ((const float4*)g)[tid];
  float4 bb = ((const float4*)be)[tid];
  float xl[4];
  xl[0] = (v.x - mean) * rstd * gg.x + bb.x;
  xl[1] = (v.y - mean) * rstd * gg.y + bb.y;
  xl[2] = (v.z - mean) * rstd * gg.z + bb.z;
  xl[3] = (v.w - mean) * rstd * gg.w + bb.w;
  float pl[8], pn[8];
  #pragma unroll
  for (int e = 0; e < 8; e++) { pl[e] = 0.f; pn[e] = 0.f; }
  #pragma unroll
  for (int j = 0; j < 4; j++) {
    int d = tid * 4 + j;
    float xv = xl[j];
    const float4* wr = (const float4*)(Wr + (size_t)d * 8);
    const float4* wn = (const float4*)(Wn + (size_t)d * 8);
    float4 a0 = wr[0], a1 = wr[1], c0 = wn[0], c1 = wn[1];
    pl[0] += xv * a0.x; pl[1] += xv * a0.y; pl[2] += xv * a0.z; pl[3] += xv * a0.w;
    pl[4] += xv * a1.x; pl[5] += xv * a1.y; pl[6] += xv * a1.z; pl[7] += xv * a1.w;
    pn[0] += xv * c0.x; pn[1] += xv * c0.y; pn[2] += xv * c0.z; pn[3] += xv * c0.w;
    pn[4] += xv * c1.x; pn[5] += xv * c1.y; pn[6] += xv * c1.z; pn[7] += xv * c1.w;
  }
  for (int o = 32; o; o >>= 1) {
    #pragma unroll
    for (int e = 0; e < 8; e++) { pl[e] += __shfl_down(pl[e], o); pn[e] += __shfl_down(pn[e], o); }
  }
  __shared__ float sl[4][8], sn[4][8];
  if ((tid & 63) == 0) {
    int w = tid >> 6;
    #pragma unroll
    for (int e = 0; e < 8; e++) { sl[w][e] = pl[e]; sn[w][e] = pn[e]; }
  }
  __syncthreads();
  if (tid == 0) {
    float noisy[8];
    #pragma unroll
    for (int e = 0; e < 8; e++) {
      float l  = sl[0][e] + sl[1][e] + sl[2][e] + sl[3][e] + br[e];
      float nn = sn[0][e] + sn[1][e] + sn[2][e] + sn[3][e] + bn[e];
      float sp = (nn > 20.f) ? nn : log1pf(expf(nn));
      noisy[e] = l + noise[(size_t)t * 8 + e] * sp;
    }
    int i0 = 0;
    for (int e = 1; e < 8; e++) if (noisy[e] > noisy[i0]) i0 = e;
    int i1 = (i0 == 0) ? 1 : 0;
    for (int e = 0; e < 8; e++) if (e != i0 && noisy[e] > noisy[i1]) i1 = e;
    float e1 = expf(noisy[i1] - noisy[i0]);
    float zz = 1.f + e1;
    gates[t * 2] = 1.f / zz; gates[t * 2 + 1] = e1 / zz;
    topidx[t * 2] = i0; topidx[t * 2 + 1] = i1;
  }
}

// ---------------- MoE bookkeeping ----------------
__global__ void k_moe_init(int* cnt, int* cnt2, int* joblist) {
  int i = blockIdx.x * 256 + threadIdx.x;
  if (i < JOBCAP) joblist[i] = -1;
  if (i < 8) { cnt[i] = 0; cnt2[i] = 0; }
}
__global__ void k_moe_count(const int* __restrict__ topidx, int* __restrict__ cnt) {
  int t = blockIdx.x * 256 + threadIdx.x;
  if (t >= TOK) return;
  atomicAdd(&cnt[topidx[t * 2]], 1);
  atomicAdd(&cnt[topidx[t * 2 + 1]], 1);
}
__global__ void k_moe_offsets(const int* __restrict__ cnt, int* __restrict__ seg) {
  if (threadIdx.x == 0) {
    int o = 0;
    for (int e = 0; e < 8; e++) { seg[e] = o; o += (cnt[e] + 127) & ~127; }
    seg[8] = o;
  }
}
__global__ void k_moe_scatter(const int* __restrict__ topidx, int* __restrict__ cnt2,
                              const int* __restrict__ seg, int* __restrict__ joblist,
                              int* __restrict__ tokpos) {
  int t = blockIdx.x * 256 + threadIdx.x;
  if (t >= TOK) return;
  #pragma unroll
  for (int s = 0; s < 2; s++) {
    int e = topidx[t * 2 + s];
    int p = atomicAdd(&cnt2[e], 1);
    int pos = seg[e] + p;
    joblist[pos] = t;
    tokpos[t * 2 + s] = pos;
  }
}
__global__ void k_combine(const float* __restrict__ y, const float* __restrict__ gates,
                          const int* __restrict__ tokpos, float* __restrict__ out) {
  int t = blockIdx.x, tid = threadIdx.x;
  int p0 = tokpos[t * 2], p1 = tokpos[t * 2 + 1];
  float g0 = gates[t * 2], g1 = gates[t * 2 + 1];
  float4 a = ((const float4*)(y + (size_t)p0 * DM))[tid];
  float4 b = ((const float4*)(y + (size_t)p1 * DM))[tid];
  float4 o;
  o.x = g0 * a.x + g1 * b.x; o.y = g0 * a.y + g1 * b.y;
  o.z = g0 * a.z + g1 * b.z; o.w = g0 * a.w + g1 * b.w;
  ((float4*)(out + (size_t)t * DM))[tid] = o;
}

// ---------------- feature mean + classifier ----------------
__global__ void k_feature(const float* __restrict__ second, float* __restrict__ feat) {
  int i = blockIdx.x * 256 + threadIdx.x;
  if (i >= 8 * DM) return;
  int b = i >> 10, d = i & 1023;
  const float* p = second + (size_t)b * SEQ * DM + d;
  float s = 0.f;
  for (int j = 0; j < SEQ; j++) s += p[(size_t)j * DM];
  feat[i] = s * (1.f / SEQ);
}
__global__ void k_cls(const float* __restrict__ feat, const float* __restrict__ Wc,
                      const float* __restrict__ bc, float* __restrict__ cls) {
  int o = blockIdx.x; int b = o / 10, n = o % 10; int l = threadIdx.x;
  float s = 0.f;
  for (int d = l; d < DM; d += 64) s += feat[b * DM + d] * Wc[(size_t)d * 10 + n];
  for (int off = 32; off; off >>= 1) s += __shfl_down(s, off);
  if (l == 0) cls[o] = s + bc[n];
}

// ---------------- launch ----------------
extern "C" void kernel_launch(void* const* d_in, const int* in_sizes, int n_in,
                              void* d_out, int out_size, void* d_ws, size_t ws_size,
                              hipStream_t stream) {
  const int*   ids    = (const int*)d_in[0];
  const float* emb    = (const float*)d_in[2];
  const float* pos    = (const float*)d_in[3];
  const float* Wq     = (const float*)d_in[4];
  const float* Wk     = (const float*)d_in[5];
  const float* Wv     = (const float*)d_in[6];
  const float* Wo     = (const float*)d_in[7];
  const float* bo     = (const float*)d_in[8];
  const float* g1     = (const float*)d_in[9];
  const float* be1    = (const float*)d_in[10];
  const float* g2     = (const float*)d_in[11];
  const float* be2    = (const float*)d_in[12];
  const float* g3     = (const float*)d_in[13];
  const float* be3    = (const float*)d_in[14];
  const float* Wr1    = (const float*)d_in[15];
  const float* br1    = (const float*)d_in[16];
  const float* Wn1    = (const float*)d_in[17];
  const float* bn1    = (const float*)d_in[18];
  const float* W1a    = (const float*)d_in[19];
  const float* b1a    = (const float*)d_in[20];
  const float* W2a    = (const float*)d_in[21];
  const float* b2a    = (const float*)d_in[22];
  const float* Wr2    = (const float*)d_in[23];
  const float* br2    = (const float*)d_in[24];
  const float* Wn2    = (const float*)d_in[25];
  const float* bn2    = (const float*)d_in[26];
  const float* W1b    = (const float*)d_in[27];
  const float* b1b    = (const float*)d_in[28];
  const float* W2b    = (const float*)d_in[29];
  const float* b2b    = (const float*)d_in[30];
  const float* noise1 = (const float*)d_in[31];
  const float* noise2 = (const float*)d_in[32];
  const float* Wc     = (const float*)d_in[33];
  const float* bc     = (const float*)d_in[34];

  char* wsp = (char*)d_ws; size_t off = 0;
  auto alloc = [&](size_t bytes) -> void* {
    void* p = wsp + off; off += (bytes + 255) & ~(size_t)255; return p;
  };
  char*  G     = (char*)alloc(180355072);              // phase-overlaid big region
  float* x     = (float*)alloc((size_t)TOK * DM * 4);
  float* x2    = (float*)alloc((size_t)TOK * DM * 4);
  u16*   xlnb  = (u16*)alloc((size_t)TOK * DM * 2);
  float* gates  = (float*)alloc(TOK * 2 * 4);
  int*   topidx = (int*)alloc(TOK * 2 * 4);
  int*   cnt    = (int*)alloc(8 * 4);
  int*   cnt2   = (int*)alloc(8 * 4);
  int*   seg    = (int*)alloc(16 * 4);
  int*   joblist= (int*)alloc(JOBCAP * 4);
  int*   tokpos = (int*)alloc(TOK * 2 * 4);
  (void)ws_size; (void)in_sizes; (void)n_in; (void)out_size;

  // attention-phase views (~160MB)
  u16* WQKVTh = (u16*)(G + 0);            // [3072][1024]
  u16* WQKVTl = (u16*)(G + 6291456);
  u16* WOTh   = (u16*)(G + 12582912);     // [1024][1024]
  u16* WOTl   = (u16*)(G + 14680064);
  u16* XLNH   = (u16*)(G + 16777216);     // [4096][1024]
  u16* XLNL   = (u16*)(G + 25165824);
  u16* QH     = (u16*)(G + 33554432);
  u16* QL     = (u16*)(G + 41943040);
  u16* KH     = (u16*)(G + 50331648);
  u16* KL     = (u16*)(G + 58720256);
  u16* VTh    = (u16*)(G + 67108864);     // [64][128][512]
  u16* VTl    = (u16*)(G + 75497472);
  u16* OH     = (u16*)(G + 83886080);     // [4096][1024]
  u16* OL     = (u16*)(G + 92274688);
  float* SC   = (float*)(G + 100663296);  // [64][512][512] f32 -> att hi/lo u16 in place
  // moe-phase views (overlay; attention buffers dead by then)
  u16*   H    = (u16*)(G + 0);            // [9216][4096] bf16
  float* Y    = (float*)(G + 75497472);   // [9216][1024] f32
  u16*   WBUF = (u16*)(G + 113246208);    // expert weights bf16, reused W1->W2

  float* out_first  = (float*)d_out;
  float* out_second = out_first + (size_t)TOK * DM;
  float* feat       = out_first + (size_t)2 * TOK * DM;
  float* cls        = feat + 8 * DM;

  dim3 tb(32, 8);
  // ---- attention phase: split-bf16 (fp32-class accuracy for router exactness) ----
  hipLaunchKernelGGL(k_tcvt_split, dim3(32, 32), tb, 0, stream, Wq, WQKVTh,            WQKVTl,            DM, DM);
  hipLaunchKernelGGL(k_tcvt_split, dim3(32, 32), tb, 0, stream, Wk, WQKVTh + 1048576,  WQKVTl + 1048576,  DM, DM);
  hipLaunchKernelGGL(k_tcvt_split, dim3(32, 32), tb, 0, stream, Wv, WQKVTh + 2097152,  WQKVTl + 2097152,  DM, DM);
  hipLaunchKernelGGL(k_tcvt_split, dim3(32, 32), tb, 0, stream, Wo, WOTh,              WOTl,              DM, DM);
  hipLaunchKernelGGL(k_embed, dim3(TOK), dim3(256), 0, stream, ids, emb, x);
  hipLaunchKernelGGL(k_ln2, dim3(TOK), dim3(256), 0, stream, x, g1, be1, XLNH, XLNL);

  GemmHArgs qa{};
  qa.Ah = XLNH; qa.Al = XLNL; qa.Bh = WQKVTh; qa.Bl = WQKVTl;
  qa.D0h = QH; qa.D0l = QL; qa.D1h = KH; qa.D1l = KL; qa.D2h = VTh; qa.D2l = VTl;
  qa.lda = DM; qa.ldb = DM; qa.K = DM;
  hipLaunchKernelGGL(gemm_h<HOP_QKV>, dim3(768), dim3(256), 0, stream, qa);

  GemmHArgs sa{};
  sa.Ah = QH; sa.Al = QL; sa.Bh = KH; sa.Bl = KL; sa.Cf = SC;
  sa.lda = DM; sa.ldb = DM; sa.K = HD;
  hipLaunchKernelGGL(gemm_h<HOP_SCORES>, dim3(4, 4, 64), dim3(256), 0, stream, sa);
  hipLaunchKernelGGL(k_softmax_h, dim3(SEQ, 64), dim3(256), 0, stream, SC);

  GemmHArgs pa{};
  pa.Ah = (const u16*)SC; pa.Bh = VTh; pa.Bl = VTl;
  pa.D0h = OH; pa.D0l = OL;
  pa.lda = 1024; pa.ldb = 512; pa.K = SEQ;
  hipLaunchKernelGGL(gemm_h<HOP_PV>, dim3(4, 1, 64), dim3(256), 0, stream, pa);

  GemmHArgs pj{};
  pj.Ah = OH; pj.Al = OL; pj.Bh = WOTh; pj.Bl = WOTl; pj.Cf = x2;
  pj.bias = bo; pj.resid = x; pj.pos = pos;
  pj.lda = DM; pj.ldb = DM; pj.K = DM;
  hipLaunchKernelGGL(gemm_h<HOP_PROJ>, dim3(256), dim3(256), 0, stream, pj);

  // ---- MoE phase (bf16 MFMA experts; router fp32) ----
  auto run_moe = [&](const float* g, const float* be, const float* Wr, const float* br,
                     const float* Wn, const float* bn, const float* noise,
                     const float* W1, const float* b1, const float* W2, const float* b2,
                     float* outp) {
    hipLaunchKernelGGL(k_ln, dim3(TOK), dim3(256), 0, stream, x2, g, be, xlnb);
    hipLaunchKernelGGL(k_router, dim3(TOK), dim3(256), 0, stream, x2, g, be, Wr, br, Wn, bn, noise, gates, topidx);
    hipLaunchKernelGGL(k_moe_init, dim3(36), dim3(256), 0, stream, cnt, cnt2, joblist);
    hipLaunchKernelGGL(k_moe_count, dim3(16), dim3(256), 0, stream, topidx, cnt);
    hipLaunchKernelGGL(k_moe_offsets, dim3(1), dim3(64), 0, stream, cnt, seg);
    hipLaunchKernelGGL(k_moe_scatter, dim3(16), dim3(256), 0, stream, topidx, cnt2, seg, joblist, tokpos);
    hipLaunchKernelGGL(k_tcvt, dim3(32, 128, 8), tb, 0, stream, W1, WBUF, DM, FF);
    GemmArgs m1{};
    m1.A = xlnb; m1.B = WBUF; m1.C = H; m1.bias = b1; m1.joblist = joblist; m1.seg = seg;
    m1.lda = DM; m1.ldb = DM; m1.K = DM;
    hipLaunchKernelGGL(gemm_k<OP_MOE1>, dim3(2304), dim3(256), 0, stream, m1);
    hipLaunchKernelGGL(k_tcvt, dim3(128, 32, 8), tb, 0, stream, W2, WBUF, FF, DM);
    GemmArgs m2{};
    m2.A = H; m2.B = WBUF; m2.C = Y; m2.bias = b2; m2.seg = seg;
    m2.lda = FF; m2.ldb = FF; m2.K = FF;
    hipLaunchKernelGGL(gemm_k<OP_MOE2>, dim3(576), dim3(256), 0, stream, m2);
    hipLaunchKernelGGL(k_combine, dim3(TOK), dim3(256), 0, stream, Y, gates, tokpos, outp);
  };
  run_moe(g2, be2, Wr1, br1, Wn1, bn1, noise1, W1a, b1a, W2a, b2a, out_first);
  run_moe(g3, be3, Wr2, br2, Wn2, bn2, noise2, W1b, b1b, W2b, b2b, out_second);

  hipLaunchKernelGGL(k_feature, dim3(32), dim3(256), 0, stream, out_second, feat);
  hipLaunchKernelGGL(k_cls, dim3(80), dim3(64), 0, stream, feat, Wc, bc, cls);
}

// Round 9
// 1228.059 us; speedup vs baseline: 1.3362x; 1.0650x over previous
//
#include <hip/hip_runtime.h>
#include <cstdint>

typedef unsigned short u16;
typedef __attribute__((ext_vector_type(8))) __bf16 bf16x8;
typedef __attribute__((ext_vector_type(4))) float f32x4;

#define TOK 4096
#define DM  1024
#define EXP 8
#define FF  4096
#define SEQ 512
#define NH  8
#define HD  128
#define JOBCAP 9216

__device__ __forceinline__ u16 f2bf(float f) {
  union { float f; unsigned int u; } v; v.f = f;
  unsigned int u = v.u;
  u += 0x7FFFu + ((u >> 16) & 1u);   // round-to-nearest-even
  return (u16)(u >> 16);
}
__device__ __forceinline__ float bf2f(u16 h) {
  union { unsigned int u; float f; } v; v.u = ((unsigned int)h) << 16; return v.f;
}

// async global->LDS, 16B per lane; dest = wave-uniform base + lane*16
__device__ __forceinline__ void gl_lds16(const u16* g, u16* l) {
  __builtin_amdgcn_global_load_lds(
      (const __attribute__((address_space(1))) unsigned int*)g,
      (__attribute__((address_space(3))) unsigned int*)l, 16, 0, 0);
}

// ---------------- embed gather ----------------
__global__ void k_embed(const int* __restrict__ ids, const float* __restrict__ emb,
                        float* __restrict__ x) {
  int t = blockIdx.x;
  int id = ids[t];
  const float4* src = (const float4*)(emb + (size_t)id * DM);
  float4* dst = (float4*)(x + (size_t)t * DM);
  dst[threadIdx.x] = src[threadIdx.x];
}

// ---------------- layernorm -> bf16 (MoE path) ----------------
__global__ void k_ln(const float* __restrict__ in, const float* __restrict__ g,
                     const float* __restrict__ be, u16* __restrict__ obf) {
  int t = blockIdx.x, tid = threadIdx.x;
  float4 v = ((const float4*)(in + (size_t)t * DM))[tid];
  float s = v.x + v.y + v.z + v.w;
  float sq = v.x*v.x + v.y*v.y + v.z*v.z + v.w*v.w;
  for (int o = 32; o; o >>= 1) { s += __shfl_down(s, o); sq += __shfl_down(sq, o); }
  __shared__ float ss[4], sqs[4];
  if ((tid & 63) == 0) { ss[tid >> 6] = s; sqs[tid >> 6] = sq; }
  __syncthreads();
  s  = ss[0] + ss[1] + ss[2] + ss[3];
  sq = sqs[0] + sqs[1] + sqs[2] + sqs[3];
  float mean = s * (1.f / DM);
  float var  = sq * (1.f / DM) - mean * mean;
  float rstd = rsqrtf(var + 1e-5f);
  float4 gg = ((const float4*)g)[tid];
  float4 bb = ((const float4*)be)[tid];
  ushort4 u;
  u.x = f2bf((v.x - mean) * rstd * gg.x + bb.x);
  u.y = f2bf((v.y - mean) * rstd * gg.y + bb.y);
  u.z = f2bf((v.z - mean) * rstd * gg.z + bb.z);
  u.w = f2bf((v.w - mean) * rstd * gg.w + bb.w);
  ((ushort4*)(obf + (size_t)t * DM))[tid] = u;
}

// ---------------- layernorm -> hi/lo bf16 pair (attention path) ----------------
__global__ void k_ln2(const float* __restrict__ in, const float* __restrict__ g,
                      const float* __restrict__ be, u16* __restrict__ oh,
                      u16* __restrict__ ol) {
  int t = blockIdx.x, tid = threadIdx.x;
  float4 v = ((const float4*)(in + (size_t)t * DM))[tid];
  float s = v.x + v.y + v.z + v.w;
  float sq = v.x*v.x + v.y*v.y + v.z*v.z + v.w*v.w;
  for (int o = 32; o; o >>= 1) { s += __shfl_down(s, o); sq += __shfl_down(sq, o); }
  __shared__ float ss[4], sqs[4];
  if ((tid & 63) == 0) { ss[tid >> 6] = s; sqs[tid >> 6] = sq; }
  __syncthreads();
  s  = ss[0] + ss[1] + ss[2] + ss[3];
  sq = sqs[0] + sqs[1] + sqs[2] + sqs[3];
  float mean = s * (1.f / DM);
  float var  = sq * (1.f / DM) - mean * mean;
  float rstd = rsqrtf(var + 1e-5f);
  float4 gg = ((const float4*)g)[tid];
  float4 bb = ((const float4*)be)[tid];
  float o4[4];
  o4[0] = (v.x - mean) * rstd * gg.x + bb.x;
  o4[1] = (v.y - mean) * rstd * gg.y + bb.y;
  o4[2] = (v.z - mean) * rstd * gg.z + bb.z;
  o4[3] = (v.w - mean) * rstd * gg.w + bb.w;
  ushort4 uh, ul;
  u16* ph = (u16*)&uh; u16* pl = (u16*)&ul;
  #pragma unroll
  for (int i = 0; i < 4; i++) {
    u16 hi = f2bf(o4[i]); ph[i] = hi; pl[i] = f2bf(o4[i] - bf2f(hi));
  }
  ((ushort4*)(oh + (size_t)t * DM))[tid] = uh;
  ((ushort4*)(ol + (size_t)t * DM))[tid] = ul;
}

// ---------------- transpose f32 [K,N] -> hi/lo bf16 [N,K] ----------------
__global__ void k_tcvt_split(const float* __restrict__ src, u16* __restrict__ dh,
                             u16* __restrict__ dl, int K, int N) {
  __shared__ float t[32][33];
  int k0 = blockIdx.x * 32, n0 = blockIdx.y * 32;
  int tx = threadIdx.x, ty = threadIdx.y;
  #pragma unroll
  for (int i = 0; i < 4; i++) t[ty + 8*i][tx] = src[(size_t)(k0 + ty + 8*i) * N + n0 + tx];
  __syncthreads();
  int u = ty * 32 + tx;
  int r = u >> 3, kq = u & 7;
  ushort4 oh, ol;
  u16* ph = (u16*)&oh; u16* pl = (u16*)&ol;
  #pragma unroll
  for (int i = 0; i < 4; i++) {
    float v = t[kq*4+i][r];
    u16 hi = f2bf(v); ph[i] = hi; pl[i] = f2bf(v - bf2f(hi));
  }
  *(ushort4*)&dh[(size_t)(n0 + r) * K + k0 + kq*4] = oh;
  *(ushort4*)&dl[(size_t)(n0 + r) * K + k0 + kq*4] = ol;
}

// ---------------- transpose f32 [K,N] -> bf16 [N,K], z-batched (MoE weights) ----------------
__global__ void k_tcvt(const float* __restrict__ src, u16* __restrict__ dst, int K, int N) {
  __shared__ float t[32][33];
  size_t zoff = (size_t)blockIdx.z * K * N;
  src += zoff;
  u16* d = dst + zoff;
  int k0 = blockIdx.x * 32, n0 = blockIdx.y * 32;
  int tx = threadIdx.x, ty = threadIdx.y;
  #pragma unroll
  for (int i = 0; i < 4; i++) t[ty + 8*i][tx] = src[(size_t)(k0 + ty + 8*i) * N + n0 + tx];
  __syncthreads();
  int u = ty * 32 + tx;
  int r = u >> 3, kq = u & 7;
  ushort4 o;
  o.x = f2bf(t[kq*4+0][r]); o.y = f2bf(t[kq*4+1][r]);
  o.z = f2bf(t[kq*4+2][r]); o.w = f2bf(t[kq*4+3][r]);
  *(ushort4*)&d[(size_t)(n0 + r) * K + k0 + kq*4] = o;
}

// ---------------- causal softmax f32 -> att hi/lo bf16 in place ----------------
__global__ void k_softmax_h(float* __restrict__ scores) {
  int q = blockIdx.x, bh = blockIdx.y, tid = threadIdx.x;
  float* row = scores + ((size_t)bh * 512 + q) * 512;
  u16* orow = (u16*)row;
  const float scale = 0.088388347648318447f; // 128^-0.5
  int j0 = tid * 2;
  float v0 = -1e30f, v1 = -1e30f;
  if (j0 <= q)     v0 = row[j0] * scale;
  if (j0 + 1 <= q) v1 = row[j0 + 1] * scale;
  float m = fmaxf(v0, v1);
  for (int o = 32; o; o >>= 1) m = fmaxf(m, __shfl_down(m, o));
  __shared__ float sm[4], ssum[4];
  if ((tid & 63) == 0) sm[tid >> 6] = m;
  __syncthreads();
  m = fmaxf(fmaxf(sm[0], sm[1]), fmaxf(sm[2], sm[3]));
  float p0 = (j0 <= q)     ? expf(v0 - m) : 0.f;
  float p1 = (j0 + 1 <= q) ? expf(v1 - m) : 0.f;
  float s = p0 + p1;
  for (int o = 32; o; o >>= 1) s += __shfl_down(s, o);
  if ((tid & 63) == 0) ssum[tid >> 6] = s;
  __syncthreads();
  s = ssum[0] + ssum[1] + ssum[2] + ssum[3];
  float inv = 1.f / s;
  float pi0 = p0 * inv, pi1 = p1 * inv;
  u16 h0 = f2bf(pi0), h1 = f2bf(pi1);
  orow[j0]       = h0; orow[j0 + 1]       = h1;
  orow[512 + j0] = f2bf(pi0 - bf2f(h0));
  orow[512 + j0 + 1] = f2bf(pi1 - bf2f(h1));
}

// ---------------- split-bf16 3-pass MFMA GEMM (attention path, fp32-class accuracy) ----------------
// C = Ah*Bh + Ah*Bl + Al*Bh  (Al*Bl term ~2^-18 rel, below split-rounding floor).
constexpr int HOP_QKV    = 0;
constexpr int HOP_SCORES = 1;
constexpr int HOP_PV     = 2;
constexpr int HOP_PROJ   = 3;

struct GemmHArgs {
  const u16 *Ah, *Al, *Bh, *Bl;
  u16 *D0h, *D0l, *D1h, *D1l, *D2h, *D2l;
  float *Cf;
  const float *bias, *resid, *pos;
  int lda, ldb, K;
};

template<int OP>
__launch_bounds__(256)
__global__ void gemm_h(GemmHArgs p) {
  int bx, by, z;
  if constexpr (OP == HOP_QKV) {         // 768 blocks: XCD c -> by in [3c,3c+3), bx fastest
    int bid = blockIdx.x; int xcd = bid & 7, slot = bid >> 3;
    by = xcd * 3 + (slot >> 5); bx = slot & 31; z = 0;
  } else if constexpr (OP == HOP_PROJ) { // 256 blocks: XCD c -> by=c, bx fastest
    int bid = blockIdx.x; by = bid & 7; bx = bid >> 3; z = 0;
  } else if constexpr (OP == HOP_SCORES) { // dense triangular: 10 tiles x 64 bh
    int bid = blockIdx.x; z = bid / 10; int t = bid % 10;
    bx = (t >= 6) ? 3 : (t >= 3) ? 2 : (t >= 1) ? 1 : 0;
    by = t - ((bx * (bx + 1)) >> 1);
  } else {
    bx = blockIdx.x; by = blockIdx.y; z = blockIdx.z;
  }

  const u16 *Ahb, *Alb, *Bhb, *Blb;
  if constexpr (OP == HOP_SCORES) {
    size_t off = (size_t)(z >> 3) * 524288 + (size_t)(z & 7) * 128;
    Ahb = p.Ah + off; Alb = p.Al + off; Bhb = p.Bh + off; Blb = p.Bl + off;
  } else if constexpr (OP == HOP_PV) {
    size_t aoff = (size_t)z * 524288;      // att u16 view [z][512][1024]
    Ahb = p.Ah + aoff; Alb = p.Ah + aoff + 512;
    size_t boff = (size_t)z * 65536;       // VT [z][128][512]
    Bhb = p.Bh + boff; Blb = p.Bl + boff;
  } else {
    Ahb = p.Ah; Alb = p.Al; Bhb = p.Bh; Blb = p.Bl;
  }

  int kmax = p.K;
  if constexpr (OP == HOP_PV) { int lim = bx * 128 + 128; kmax = lim < p.K ? lim : p.K; }
  int nt = kmax >> 5;

  __shared__ __align__(16) u16 As[2 * 4096];
  __shared__ __align__(16) u16 Bs[2 * 4096];

  int tid = threadIdx.x, lane = tid & 63, wid = tid >> 6;
  int srow = wid * 16 + (lane >> 2), skoff = (lane & 3) * 8;
  int lo0 = (wid * 16) * 32, lo1 = ((wid + 4) * 16) * 32;
  int wr = wid >> 1, wc = wid & 1, fm = lane & 15, fk = (lane >> 4) * 8;

  f32x4 acc[4][4] = {};
  const size_t lda = p.lda, ldb = p.ldb;

  #pragma unroll 1
  for (int pass = 0; pass < 3; ++pass) {
    const u16* Ab = (pass < 2) ? Ahb : Alb;
    const u16* Bb = (pass & 1) ? Blb : Bhb;
    const u16* aptr0 = Ab + (size_t)(bx * 128 + srow) * lda + skoff;
    const u16* aptr1 = Ab + (size_t)(bx * 128 + 64 + srow) * lda + skoff;
    const u16* bptr0 = Bb + (size_t)(by * 128 + srow) * ldb + skoff;
    const u16* bptr1 = Bb + (size_t)(by * 128 + 64 + srow) * ldb + skoff;

    gl_lds16(aptr0, &As[lo0]); gl_lds16(aptr1, &As[lo1]);
    gl_lds16(bptr0, &Bs[lo0]); gl_lds16(bptr1, &Bs[lo1]);
    __syncthreads();
    int cur = 0;
    for (int t = 0; t < nt; ++t) {
      if (t + 1 < nt) {
        int nxt = (cur ^ 1) * 4096;
        int k0 = (t + 1) * 32;
        gl_lds16(aptr0 + k0, &As[nxt + lo0]); gl_lds16(aptr1 + k0, &As[nxt + lo1]);
        gl_lds16(bptr0 + k0, &Bs[nxt + lo0]); gl_lds16(bptr1 + k0, &Bs[nxt + lo1]);
      }
      int cb = cur * 4096;
      bf16x8 af[4], bfr[4];
      #pragma unroll
      for (int i = 0; i < 4; ++i) {
        af[i]  = *(const bf16x8*)&As[cb + (wr * 64 + i * 16 + fm) * 32 + fk];
        bfr[i] = *(const bf16x8*)&Bs[cb + (wc * 64 + i * 16 + fm) * 32 + fk];
      }
      #pragma unroll
      for (int mi = 0; mi < 4; ++mi)
        #pragma unroll
        for (int ni = 0; ni < 4; ++ni)
          acc[mi][ni] = __builtin_amdgcn_mfma_f32_16x16x32_bf16(af[mi], bfr[ni], acc[mi][ni], 0, 0, 0);
      __syncthreads();
      cur ^= 1;
    }
  }

  int rb = (lane >> 4) * 4, cl = lane & 15;
  #pragma unroll
  for (int mi = 0; mi < 4; ++mi)
    #pragma unroll
    for (int ni = 0; ni < 4; ++ni)
      #pragma unroll
      for (int j = 0; j < 4; ++j) {
        int m = bx * 128 + wr * 64 + mi * 16 + rb + j;
        int n = by * 128 + wc * 64 + ni * 16 + cl;
        float v = acc[mi][ni][j];
        if constexpr (OP == HOP_QKV) {
          u16 hi = f2bf(v); u16 lo = f2bf(v - bf2f(hi));
          int sel = n >> 10, nn = n & 1023;
          if (sel == 0) {
            p.D0h[(size_t)m * DM + nn] = hi; p.D0l[(size_t)m * DM + nn] = lo;
          } else if (sel == 1) {
            p.D1h[(size_t)m * DM + nn] = hi; p.D1l[(size_t)m * DM + nn] = lo;
          } else {
            size_t idx = (size_t)((m >> 9) * 8 + (nn >> 7)) * 65536 + (size_t)(nn & 127) * 512 + (m & 511);
            p.D2h[idx] = hi; p.D2l[idx] = lo;
          }
        } else if constexpr (OP == HOP_SCORES) {
          p.Cf[(size_t)z * 262144 + (size_t)m * 512 + n] = v;
        } else if constexpr (OP == HOP_PV) {
          u16 hi = f2bf(v); u16 lo = f2bf(v - bf2f(hi));
          size_t idx = (size_t)(z >> 3) * 524288 + (size_t)m * 1024 + (size_t)(z & 7) * 128 + n;
          p.D0h[idx] = hi; p.D0l[idx] = lo;
        } else { // HOP_PROJ
          size_t idx = (size_t)m * 1024 + n;
          p.Cf[idx] = v + p.bias[n] + p.resid[idx] + p.pos[(size_t)(m & 511) * 1024 + n];
        }
      }
}

// ---------------- bf16 MFMA 128x128 TN GEMM, 2-phase dbuf + XCD-chunked 1D grid (MoE) ----------------
constexpr int OP_MOE1 = 0;
constexpr int OP_MOE2 = 1;

struct GemmArgs {
  const u16* A; const u16* B; void* C;
  const float* bias;
  const int* joblist; const int* seg;
  int lda, ldb, K;
};

template<int OP>
__launch_bounds__(256)
__global__ void gemm_k(GemmArgs p) {
  int bid = blockIdx.x;
  int xcd = bid & 7, slot = bid >> 3;
  int bx, by;
  if constexpr (OP == OP_MOE1) {
    by = xcd * 4 + (slot & 3);
    bx = slot >> 2;
  } else {
    bx = xcd * 9 + (slot >> 3);
    by = slot & 7;
  }
  int r0g = bx * 128;
  if (r0g >= p.seg[8]) return;
  int z = 0;
  #pragma unroll
  for (int e = 1; e < 8; ++e) z += (r0g >= p.seg[e]) ? 1 : 0;
  const u16* Bbase = p.B + (size_t)z * 4194304;

  __shared__ __align__(16) u16 As[2 * 4096];
  __shared__ __align__(16) u16 Bs[2 * 4096];

  int tid = threadIdx.x;
  int lane = tid & 63, wid = tid >> 6;

  int srow = wid * 16 + (lane >> 2);
  int skoff = (lane & 3) * 8;

  const u16 *aptr0, *aptr1;
  if constexpr (OP == OP_MOE1) {
    int j0 = p.joblist[r0g + srow];
    int j1 = p.joblist[r0g + 64 + srow];
    aptr0 = p.A + (size_t)(j0 < 0 ? 0 : j0) * p.lda + skoff;
    aptr1 = p.A + (size_t)(j1 < 0 ? 0 : j1) * p.lda + skoff;
  } else {
    aptr0 = p.A + (size_t)(r0g + srow) * p.lda + skoff;
    aptr1 = p.A + (size_t)(r0g + 64 + srow) * p.lda + skoff;
  }
  const u16* bptr0 = Bbase + (size_t)(by * 128 + srow) * p.ldb + skoff;
  const u16* bptr1 = Bbase + (size_t)(by * 128 + 64 + srow) * p.ldb + skoff;

  int lo0 = (wid * 16) * 32;
  int lo1 = ((wid + 4) * 16) * 32;

  int wr = wid >> 1, wc = wid & 1;
  int fm = lane & 15;
  int fk = (lane >> 4) * 8;

  f32x4 acc[4][4] = {};
  int nt = p.K >> 5;

  gl_lds16(aptr0, &As[lo0]); gl_lds16(aptr1, &As[lo1]);
  gl_lds16(bptr0, &Bs[lo0]); gl_lds16(bptr1, &Bs[lo1]);
  __syncthreads();

  int cur = 0;
  for (int t = 0; t < nt; ++t) {
    if (t + 1 < nt) {
      int nxt = (cur ^ 1) * 4096;
      int k0 = (t + 1) * 32;
      gl_lds16(aptr0 + k0, &As[nxt + lo0]); gl_lds16(aptr1 + k0, &As[nxt + lo1]);
      gl_lds16(bptr0 + k0, &Bs[nxt + lo0]); gl_lds16(bptr1 + k0, &Bs[nxt + lo1]);
    }
    int cb = cur * 4096;
    bf16x8 af[4], bfr[4];
    #pragma unroll
    for (int i = 0; i < 4; ++i) {
      af[i]  = *(const bf16x8*)&As[cb + (wr * 64 + i * 16 + fm) * 32 + fk];
      bfr[i] = *(const bf16x8*)&Bs[cb + (wc * 64 + i * 16 + fm) * 32 + fk];
    }
    #pragma unroll
    for (int mi = 0; mi < 4; ++mi)
      #pragma unroll
      for (int ni = 0; ni < 4; ++ni)
        acc[mi][ni] = __builtin_amdgcn_mfma_f32_16x16x32_bf16(af[mi], bfr[ni], acc[mi][ni], 0, 0, 0);
    __syncthreads();
    cur ^= 1;
  }

  int rb = (lane >> 4) * 4;
  int cl = lane & 15;
  #pragma unroll
  for (int mi = 0; mi < 4; ++mi)
    #pragma unroll
    for (int ni = 0; ni < 4; ++ni)
      #pragma unroll
      for (int j = 0; j < 4; ++j) {
        int m = r0g + wr * 64 + mi * 16 + rb + j;
        int n = by * 128 + wc * 64 + ni * 16 + cl;
        float v = acc[mi][ni][j];
        if constexpr (OP == OP_MOE1) {
          float t2 = v + p.bias[(size_t)z * FF + n];
          t2 = t2 > 0.f ? t2 : 0.f;
          ((u16*)p.C)[(size_t)m * FF + n] = f2bf(t2);
        } else {
          ((float*)p.C)[(size_t)m * DM + n] = v + p.bias[(size_t)z * DM + n];
        }
      }
}

// ---------------- router: inline fp32 LN + logits + noisy top-2 + gates ----------------
__global__ void k_router(const float* __restrict__ xin, const float* __restrict__ g,
                         const float* __restrict__ be,
                         const float* __restrict__ Wr, const float* __restrict__ br,
                         const float* __restrict__ Wn, const float* __restrict__ bn,
                         const float* __restrict__ noise,
                         float* __restrict__ gates, int* __restrict__ topidx) {
  int t = blockIdx.x, tid = threadIdx.x;
  float4 v = ((const float4*)(xin + (size_t)t * DM))[tid];
  float s = v.x + v.y + v.z + v.w;
  float sq = v.x*v.x + v.y*v.y + v.z*v.z + v.w*v.w;
  for (int o = 32; o; o >>= 1) { s += __shfl_down(s, o); sq += __shfl_down(sq, o); }
  __shared__ float ss[4], sqs[4];
  if ((tid & 63) == 0) { ss[tid >> 6] = s; sqs[tid >> 6] = sq; }
  __syncthreads();
  s  = ss[0] + ss[1] + ss[2] + ss[3];
  sq = sqs[0] + sqs[1] + sqs[2] + sqs[3];
  float mean = s * (1.f / DM);
  float var  = sq * (1.f / DM) - mean * mean;
  float rstd = rsqrtf(var + 1e-5f);
  float4 gg = ((const float4*)g)[tid];
  float4 bb = ((const float4*)be)[tid];
  float xl[4];
  xl[0] = (v.x - mean) * rstd * gg.x + bb.x;
  xl[1] = (v.y - mean) * rstd * gg.y + bb.y;
  xl[2] = (v.z - mean) * rstd * gg.z + bb.z;
  xl[3] = (v.w - mean) * rstd * gg.w + bb.w;
  float pl[8], pn[8];
  #pragma unroll
  for (int e = 0; e < 8; e++) { pl[e] = 0.f; pn[e] = 0.f; }
  #pragma unroll
  for (int j = 0; j < 4; j++) {
    int d = tid * 4 + j;
    float xv = xl[j];
    const float4* wr = (const float4*)(Wr + (size_t)d * 8);
    const float4* wn = (const float4*)(Wn + (size_t)d * 8);
    float4 a0 = wr[0], a1 = wr[1], c0 = wn[0], c1 = wn[1];
    pl[0] += xv * a0.x; pl[1] += xv * a0.y; pl[2] += xv * a0.z; pl[3] += xv * a0.w;
    pl[4] += xv * a1.x; pl[5] += xv * a1.y; pl[6] += xv * a1.z; pl[7] += xv * a1.w;
    pn[0] += xv * c0.x; pn[1] += xv * c0.y; pn[2] += xv * c0.z; pn[3] += xv * c0.w;
    pn[4] += xv * c1.x; pn[5] += xv * c1.y; pn[6] += xv * c1.z; pn[7] += xv * c1.w;
  }
  for (int o = 32; o; o >>= 1) {
    #pragma unroll
    for (int e = 0; e < 8; e++) { pl[e] += __shfl_down(pl[e], o); pn[e] += __shfl_down(pn[e], o); }
  }
  __shared__ float sl[4][8], sn[4][8];
  if ((tid & 63) == 0) {
    int w = tid >> 6;
    #pragma unroll
    for (int e = 0; e < 8; e++) { sl[w][e] = pl[e]; sn[w][e] = pn[e]; }
  }
  __syncthreads();
  if (tid == 0) {
    float noisy[8];
    #pragma unroll
    for (int e = 0; e < 8; e++) {
      float l  = sl[0][e] + sl[1][e] + sl[2][e] + sl[3][e] + br[e];
      float nn = sn[0][e] + sn[1][e] + sn[2][e] + sn[3][e] + bn[e];
      float sp = (nn > 20.f) ? nn : log1pf(expf(nn));
      noisy[e] = l + noise[(size_t)t * 8 + e] * sp;
    }
    int i0 = 0;
    for (int e = 1; e < 8; e++) if (noisy[e] > noisy[i0]) i0 = e;
    int i1 = (i0 == 0) ? 1 : 0;
    for (int e = 0; e < 8; e++) if (e != i0 && noisy[e] > noisy[i1]) i1 = e;
    float e1 = expf(noisy[i1] - noisy[i0]);
    float zz = 1.f + e1;
    gates[t * 2] = 1.f / zz; gates[t * 2 + 1] = e1 / zz;
    topidx[t * 2] = i0; topidx[t * 2 + 1] = i1;
  }
}

// ---------------- MoE bookkeeping ----------------
__global__ void k_moe_init(int* cnt, int* cnt2, int* joblist) {
  int i = blockIdx.x * 256 + threadIdx.x;
  if (i < JOBCAP) joblist[i] = -1;
  if (i < 8) { cnt[i] = 0; cnt2[i] = 0; }
}
__global__ void k_moe_count(const int* __restrict__ topidx, int* __restrict__ cnt) {
  int t = blockIdx.x * 256 + threadIdx.x;
  if (t >= TOK) return;
  atomicAdd(&cnt[topidx[t * 2]], 1);
  atomicAdd(&cnt[topidx[t * 2 + 1]], 1);
}
__global__ void k_moe_offsets(const int* __restrict__ cnt, int* __restrict__ seg) {
  if (threadIdx.x == 0) {
    int o = 0;
    for (int e = 0; e < 8; e++) { seg[e] = o; o += (cnt[e] + 127) & ~127; }
    seg[8] = o;
  }
}
__global__ void k_moe_scatter(const int* __restrict__ topidx, int* __restrict__ cnt2,
                              const int* __restrict__ seg, int* __restrict__ joblist,
                              int* __restrict__ tokpos) {
  int t = blockIdx.x * 256 + threadIdx.x;
  if (t >= TOK) return;
  #pragma unroll
  for (int s = 0; s < 2; s++) {
    int e = topidx[t * 2 + s];
    int p = atomicAdd(&cnt2[e], 1);
    int pos = seg[e] + p;
    joblist[pos] = t;
    tokpos[t * 2 + s] = pos;
  }
}
__global__ void k_combine(const float* __restrict__ y, const float* __restrict__ gates,
                          const int* __restrict__ tokpos, float* __restrict__ out) {
  int t = blockIdx.x, tid = threadIdx.x;
  int p0 = tokpos[t * 2], p1 = tokpos[t * 2 + 1];
  float g0 = gates[t * 2], g1 = gates[t * 2 + 1];
  float4 a = ((const float4*)(y + (size_t)p0 * DM))[tid];
  float4 b = ((const float4*)(y + (size_t)p1 * DM))[tid];
  float4 o;
  o.x = g0 * a.x + g1 * b.x; o.y = g0 * a.y + g1 * b.y;
  o.z = g0 * a.z + g1 * b.z; o.w = g0 * a.w + g1 * b.w;
  ((float4*)(out + (size_t)t * DM))[tid] = o;
}

// ---------------- feature mean (two-stage) + classifier ----------------
__global__ void k_feat1(const float* __restrict__ second, float* __restrict__ part) {
  int b = blockIdx.x, c = blockIdx.y, tid = threadIdx.x;
  const float* p = second + ((size_t)b * SEQ + (size_t)c * 64) * DM;
  float4 s = {0.f, 0.f, 0.f, 0.f};
  for (int j = 0; j < 64; ++j) {
    float4 v = ((const float4*)(p + (size_t)j * DM))[tid];
    s.x += v.x; s.y += v.y; s.z += v.z; s.w += v.w;
  }
  ((float4*)(part + (size_t)(b * 8 + c) * DM))[tid] = s;
}
__global__ void k_feat2(const float* __restrict__ part, float* __restrict__ feat) {
  int i = blockIdx.x * 256 + threadIdx.x;   // 8192 = 8*1024
  int b = i >> 10, d = i & 1023;
  float s = 0.f;
  #pragma unroll
  for (int c = 0; c < 8; ++c) s += part[(size_t)(b * 8 + c) * DM + d];
  feat[i] = s * (1.f / SEQ);
}
__global__ void k_cls(const float* __restrict__ feat, const float* __restrict__ Wc,
                      const float* __restrict__ bc, float* __restrict__ cls) {
  int o = blockIdx.x; int b = o / 10, n = o % 10; int l = threadIdx.x;
  float s = 0.f;
  for (int d = l; d < DM; d += 64) s += feat[b * DM + d] * Wc[(size_t)d * 10 + n];
  for (int off = 32; off; off >>= 1) s += __shfl_down(s, off);
  if (l == 0) cls[o] = s + bc[n];
}

// ---------------- launch ----------------
extern "C" void kernel_launch(void* const* d_in, const int* in_sizes, int n_in,
                              void* d_out, int out_size, void* d_ws, size_t ws_size,
                              hipStream_t stream) {
  const int*   ids    = (const int*)d_in[0];
  const float* emb    = (const float*)d_in[2];
  const float* pos    = (const float*)d_in[3];
  const float* Wq     = (const float*)d_in[4];
  const float* Wk     = (const float*)d_in[5];
  const float* Wv     = (const float*)d_in[6];
  const float* Wo     = (const float*)d_in[7];
  const float* bo     = (const float*)d_in[8];
  const float* g1     = (const float*)d_in[9];
  const float* be1    = (const float*)d_in[10];
  const float* g2     = (const float*)d_in[11];
  const float* be2    = (const float*)d_in[12];
  const float* g3     = (const float*)d_in[13];
  const float* be3    = (const float*)d_in[14];
  const float* Wr1    = (const float*)d_in[15];
  const float* br1    = (const float*)d_in[16];
  const float* Wn1    = (const float*)d_in[17];
  const float* bn1    = (const float*)d_in[18];
  const float* W1a    = (const float*)d_in[19];
  const float* b1a    = (const float*)d_in[20];
  const float* W2a    = (const float*)d_in[21];
  const float* b2a    = (const float*)d_in[22];
  const float* Wr2    = (const float*)d_in[23];
  const float* br2    = (const float*)d_in[24];
  const float* Wn2    = (const float*)d_in[25];
  const float* bn2    = (const float*)d_in[26];
  const float* W1b    = (const float*)d_in[27];
  const float* b1b    = (const float*)d_in[28];
  const float* W2b    = (const float*)d_in[29];
  const float* b2b    = (const float*)d_in[30];
  const float* noise1 = (const float*)d_in[31];
  const float* noise2 = (const float*)d_in[32];
  const float* Wc     = (const float*)d_in[33];
  const float* bc     = (const float*)d_in[34];

  char* wsp = (char*)d_ws; size_t off = 0;
  auto alloc = [&](size_t bytes) -> void* {
    void* p = wsp + off; off += (bytes + 255) & ~(size_t)255; return p;
  };
  char*  G     = (char*)alloc(180355072);              // phase-overlaid big region
  float* x     = (float*)alloc((size_t)TOK * DM * 4);
  float* x2    = (float*)alloc((size_t)TOK * DM * 4);
  u16*   xlnb  = (u16*)alloc((size_t)TOK * DM * 2);
  float* gates  = (float*)alloc(TOK * 2 * 4);
  int*   topidx = (int*)alloc(TOK * 2 * 4);
  int*   cnt    = (int*)alloc(8 * 4);
  int*   cnt2   = (int*)alloc(8 * 4);
  int*   seg    = (int*)alloc(16 * 4);
  int*   joblist= (int*)alloc(JOBCAP * 4);
  int*   tokpos = (int*)alloc(TOK * 2 * 4);
  float* fpart  = (float*)alloc(64 * DM * 4);
  (void)ws_size; (void)in_sizes; (void)n_in; (void)out_size;

  // attention-phase views (~160MB)
  u16* WQKVTh = (u16*)(G + 0);            // [3072][1024]
  u16* WQKVTl = (u16*)(G + 6291456);
  u16* WOTh   = (u16*)(G + 12582912);     // [1024][1024]
  u16* WOTl   = (u16*)(G + 14680064);
  u16* XLNH   = (u16*)(G + 16777216);     // [4096][1024]
  u16* XLNL   = (u16*)(G + 25165824);
  u16* QH     = (u16*)(G + 33554432);
  u16* QL     = (u16*)(G + 41943040);
  u16* KH     = (u16*)(G + 50331648);
  u16* KL     = (u16*)(G + 58720256);
  u16* VTh    = (u16*)(G + 67108864);     // [64][128][512]
  u16* VTl    = (u16*)(G + 75497472);
  u16* OH     = (u16*)(G + 83886080);     // [4096][1024]
  u16* OL     = (u16*)(G + 92274688);
  float* SC   = (float*)(G + 100663296);  // [64][512][512] f32 -> att hi/lo u16 in place
  // moe-phase views (overlay; attention buffers dead by then)
  u16*   H    = (u16*)(G + 0);            // [9216][4096] bf16
  float* Y    = (float*)(G + 75497472);   // [9216][1024] f32
  u16*   WBUF = (u16*)(G + 113246208);    // expert weights bf16, reused W1->W2

  float* out_first  = (float*)d_out;
  float* out_second = out_first + (size_t)TOK * DM;
  float* feat       = out_first + (size_t)2 * TOK * DM;
  float* cls        = feat + 8 * DM;

  dim3 tb(32, 8);
  // ---- attention phase: split-bf16 3-pass (fp32-class accuracy for router exactness) ----
  hipLaunchKernelGGL(k_tcvt_split, dim3(32, 32), tb, 0, stream, Wq, WQKVTh,            WQKVTl,            DM, DM);
  hipLaunchKernelGGL(k_tcvt_split, dim3(32, 32), tb, 0, stream, Wk, WQKVTh + 1048576,  WQKVTl + 1048576,  DM, DM);
  hipLaunchKernelGGL(k_tcvt_split, dim3(32, 32), tb, 0, stream, Wv, WQKVTh + 2097152,  WQKVTl + 2097152,  DM, DM);
  hipLaunchKernelGGL(k_tcvt_split, dim3(32, 32), tb, 0, stream, Wo, WOTh,              WOTl,              DM, DM);
  hipLaunchKernelGGL(k_embed, dim3(TOK), dim3(256), 0, stream, ids, emb, x);
  hipLaunchKernelGGL(k_ln2, dim3(TOK), dim3(256), 0, stream, x, g1, be1, XLNH, XLNL);

  GemmHArgs qa{};
  qa.Ah = XLNH; qa.Al = XLNL; qa.Bh = WQKVTh; qa.Bl = WQKVTl;
  qa.D0h = QH; qa.D0l = QL; qa.D1h = KH; qa.D1l = KL; qa.D2h = VTh; qa.D2l = VTl;
  qa.lda = DM; qa.ldb = DM; qa.K = DM;
  hipLaunchKernelGGL(gemm_h<HOP_QKV>, dim3(768), dim3(256), 0, stream, qa);

  GemmHArgs sa{};
  sa.Ah = QH; sa.Al = QL; sa.Bh = KH; sa.Bl = KL; sa.Cf = SC;
  sa.lda = DM; sa.ldb = DM; sa.K = HD;
  hipLaunchKernelGGL(gemm_h<HOP_SCORES>, dim3(640), dim3(256), 0, stream, sa);
  hipLaunchKernelGGL(k_softmax_h, dim3(SEQ, 64), dim3(256), 0, stream, SC);

  GemmHArgs pa{};
  pa.Ah = (const u16*)SC; pa.Bh = VTh; pa.Bl = VTl;
  pa.D0h = OH; pa.D0l = OL;
  pa.lda = 1024; pa.ldb = 512; pa.K = SEQ;
  hipLaunchKernelGGL(gemm_h<HOP_PV>, dim3(4, 1, 64), dim3(256), 0, stream, pa);

  GemmHArgs pj{};
  pj.Ah = OH; pj.Al = OL; pj.Bh = WOTh; pj.Bl = WOTl; pj.Cf = x2;
  pj.bias = bo; pj.resid = x; pj.pos = pos;
  pj.lda = DM; pj.ldb = DM; pj.K = DM;
  hipLaunchKernelGGL(gemm_h<HOP_PROJ>, dim3(256), dim3(256), 0, stream, pj);

  // ---- MoE phase (bf16 MFMA experts; router fp32) ----
  auto run_moe = [&](const float* g, const float* be, const float* Wr, const float* br,
                     const float* Wn, const float* bn, const float* noise,
                     const float* W1, const float* b1, const float* W2, const float* b2,
                     float* outp) {
    hipLaunchKernelGGL(k_ln, dim3(TOK), dim3(256), 0, stream, x2, g, be, xlnb);
    hipLaunchKernelGGL(k_router, dim3(TOK), dim3(256), 0, stream, x2, g, be, Wr, br, Wn, bn, noise, gates, topidx);
    hipLaunchKernelGGL(k_moe_init, dim3(36), dim3(256), 0, stream, cnt, cnt2, joblist);
    hipLaunchKernelGGL(k_moe_count, dim3(16), dim3(256), 0, stream, topidx, cnt);
    hipLaunchKernelGGL(k_moe_offsets, dim3(1), dim3(64), 0, stream, cnt, seg);
    hipLaunchKernelGGL(k_moe_scatter, dim3(16), dim3(256), 0, stream, topidx, cnt2, seg, joblist, tokpos);
    hipLaunchKernelGGL(k_tcvt, dim3(32, 128, 8), tb, 0, stream, W1, WBUF, DM, FF);
    GemmArgs m1{};
    m1.A = xlnb; m1.B = WBUF; m1.C = H; m1.bias = b1; m1.joblist = joblist; m1.seg = seg;
    m1.lda = DM; m1.ldb = DM; m1.K = DM;
    hipLaunchKernelGGL(gemm_k<OP_MOE1>, dim3(2304), dim3(256), 0, stream, m1);
    hipLaunchKernelGGL(k_tcvt, dim3(128, 32, 8), tb, 0, stream, W2, WBUF, FF, DM);
    GemmArgs m2{};
    m2.A = H; m2.B = WBUF; m2.C = Y; m2.bias = b2; m2.seg = seg;
    m2.lda = FF; m2.ldb = FF; m2.K = FF;
    hipLaunchKernelGGL(gemm_k<OP_MOE2>, dim3(576), dim3(256), 0, stream, m2);
    hipLaunchKernelGGL(k_combine, dim3(TOK), dim3(256), 0, stream, Y, gates, tokpos, outp);
  };
  run_moe(g2, be2, Wr1, br1, Wn1, bn1, noise1, W1a, b1a, W2a, b2a, out_first);
  run_moe(g3, be3, Wr2, br2, Wn2, bn2, noise2, W1b, b1b, W2b, b2b, out_second);

  hipLaunchKernelGGL(k_feat1, dim3(8, 8), dim3(256), 0, stream, out_second, fpart);
  hipLaunchKernelGGL(k_feat2, dim3(32), dim3(256), 0, stream, fpart, feat);
  hipLaunchKernelGGL(k_cls, dim3(80), dim3(64), 0, stream, feat, Wc, bc, cls);
}